// Round 4
// baseline (960.123 us; speedup 1.0000x reference)
//
#include <hip/hip_runtime.h>
#include <hip/hip_bf16.h>

#define TT 2048
#define HD 2048
#define ID 2048
#define NE 8

typedef __attribute__((ext_vector_type(8))) short short8;
typedef __attribute__((ext_vector_type(4))) float f4;

__device__ __forceinline__ unsigned short b16(float f){
  union { __hip_bfloat16 b; unsigned short u; } x;
  x.b = __float2bfloat16(f);
  return x.u;
}
__device__ __forceinline__ unsigned pk2(float lo, float hi){
  return (unsigned)b16(lo) | ((unsigned)b16(hi) << 16);
}
__device__ __forceinline__ float gelu_t(float x){
  float y = 0.7978845608028654f * (x + 0.044715f * x * x * x);
  float t = 1.0f - 2.0f / (__expf(2.0f * y) + 1.0f);
  return 0.5f * x * (1.0f + t);
}
__device__ __forceinline__ void glds16(const void* g, void* l){
  __builtin_amdgcn_global_load_lds(
      (const __attribute__((address_space(1))) unsigned*)g,
      (__attribute__((address_space(3))) unsigned*)l, 16, 0, 0);
}
__device__ __forceinline__ int swzB(int n){ return (((n >> 2) & 7) ^ ((n & 3) << 1)) & 7; }

// ---------------- X fp32 -> bf16 ----------------
__global__ void k_cvtx(const float* __restrict__ X, __hip_bfloat16* __restrict__ Xb){
  int i = blockIdx.x * 256 + threadIdx.x;
  const f4* src = (const f4*)X + (size_t)i * 2;
  f4 a = src[0], b = src[1];
  uint4 o = { pk2(a[0],a[1]), pk2(a[2],a[3]), pk2(b[0],b[1]), pk2(b[2],b[3]) };
  ((uint4*)Xb)[i] = o;
}

// ---------------- routing ----------------
__global__ void k_route(const float* __restrict__ lg, const float* __restrict__ sc,
                        int* __restrict__ rid, float* __restrict__ rw){
  int t = blockIdx.x * blockDim.x + threadIdx.x;
  if (t >= TT) return;
  float l[NE];
#pragma unroll
  for (int e = 0; e < NE; e++) l[e] = lg[t * NE + e];
  float mx = l[0];
#pragma unroll
  for (int e = 1; e < NE; e++) mx = fmaxf(mx, l[e]);
  float p[NE];
#pragma unroll
  for (int e = 0; e < NE; e++) p[e] = __expf(l[e] - mx);
  int i0 = 0; float b0 = l[0];
#pragma unroll
  for (int e = 1; e < NE; e++) if (l[e] > b0){ b0 = l[e]; i0 = e; }
  int i1 = -1; float b1 = -1e30f;
#pragma unroll
  for (int e = 0; e < NE; e++) if (e != i0 && l[e] > b1){ b1 = l[e]; i1 = e; }
  float p0 = p[i0], p1 = p[i1];
  float rn = p0 + p1; rn = (rn > 0.f) ? rn : 1.f;
  rw[t*2]   = p0 / rn * sc[i0];
  rw[t*2+1] = p1 / rn * sc[i1];
  rid[t*2]  = i0;
  rid[t*2+1]= i1;
}

// ---------------- deterministic per-expert compaction ----------------
__global__ void k_lists(const int* __restrict__ rid, const float* __restrict__ rw,
                        int* __restrict__ row_tok, float* __restrict__ row_w,
                        int* __restrict__ off){
  int lane = threadIdx.x;            // 64 threads
  int ids[64]; float wv[64];
#pragma unroll
  for (int i = 0; i < 64; i++) ids[i] = rid[i * 64 + lane];
#pragma unroll
  for (int i = 0; i < 64; i++) wv[i] = rw[i * 64 + lane];
  int cnt[NE];
#pragma unroll
  for (int e = 0; e < NE; e++) cnt[e] = 0;
#pragma unroll
  for (int i = 0; i < 64; i++){
#pragma unroll
    for (int e = 0; e < NE; e++)
      cnt[e] += __popcll(__ballot(ids[i] == e));
  }
  int offs[NE + 1]; offs[0] = 0;
#pragma unroll
  for (int e = 0; e < NE; e++) offs[e + 1] = offs[e] + cnt[e];
  if (lane == 0){
#pragma unroll
    for (int e = 0; e <= NE; e++) off[e] = offs[e];
  }
  int run[NE];
#pragma unroll
  for (int e = 0; e < NE; e++) run[e] = offs[e];
  unsigned long long ltm = (1ULL << lane) - 1ULL;
#pragma unroll
  for (int i = 0; i < 64; i++){
    int id = ids[i];
    int tok = (i * 64 + lane) >> 1;
#pragma unroll
    for (int e = 0; e < NE; e++){
      unsigned long long m = __ballot(id == e);
      if (id == e){
        int pos = run[e] + __popcll(m & ltm);
        row_tok[pos] = tok;
        row_w[pos]   = wv[i];
      }
      run[e] += __popcll(m);
    }
  }
}

// -------- gate+up grouped GEMM: 128(m) x 64(n) dual tile, BK=64, depth-2 pipeline --------
__global__ __launch_bounds__(256, 3)
void k_gateup(const __hip_bfloat16* __restrict__ Xb, const float* __restrict__ Wg,
              const float* __restrict__ Wu, const int* __restrict__ row_tok,
              const int* __restrict__ off, __hip_bfloat16* __restrict__ hbuf){
  __shared__ __align__(16) char sA[2][16384];   // [128 m][64 k] bf16, slot^=(m&7)
  __shared__ __align__(16) char sBg[8192];      // [64 n][64 k] bf16, slot^=swzB(n)
  __shared__ __align__(16) char sBu[8192];
  __shared__ int s_tok[128];

  const int bid = blockIdx.x;           // 2048 = 8e x 8mt x 32nt ; e==XCD pin
  const int e  = bid & 7;
  const int mt = (bid >> 3) & 7;
  const int nt = bid >> 6;              // 0..31
  const int o0 = off[e], cnt = off[e + 1] - o0;
  if (mt * 128 >= cnt) return;
  const int p0 = o0 + mt * 128;
  const int cntL = min(128, cnt - mt * 128);
  const int tid = threadIdx.x;
  const int wid = tid >> 6, lane = tid & 63;

  if (tid < 128) s_tok[tid] = row_tok[min(p0 + tid, TT*2 - 1)];
  __syncthreads();

  // A staging sources: chunk c = wid*4+i (1KB), lane l -> row c*8+(l>>3), slot l&7
  const char* asrc[4];
#pragma unroll
  for (int i = 0; i < 4; i++){
    int c = wid * 4 + i;
    int r = c * 8 + (lane >> 3);
    asrc[i] = (const char*)Xb + (size_t)s_tok[r] * (HD * 2)
            + ((((lane & 7) ^ (lane >> 3)) & 7) << 4);
  }
  // B staging: thread -> 4 k-rows x 4 n
  const int n0 = (tid & 15) * 4;
  const int k0 = (tid >> 4) * 4;        // 0..60
  const size_t wb = (size_t)e * HD * ID + (size_t)k0 * ID + (size_t)nt * 64 + n0;
  const float* gsrc = Wg + wb;
  const float* usrc = Wu + wb;
  int bw[4];
#pragma unroll
  for (int j = 0; j < 4; j++)
    bw[j] = (n0 + j) * 128 + ((((k0 >> 3) ^ (tid & 7) ^ (j << 1)) & 7) << 4) + ((k0 & 4) << 1);

  // fragment read offsets
  const int wm = wid >> 1, wn = wid & 1;     // 2x2 waves: 64 rows x 32 cols (dual)
  const int kg = lane >> 4, ln = lane & 15;
  int aoff[2][4], boff[2][2];
#pragma unroll
  for (int ks = 0; ks < 2; ks++){
    int qs = ks * 4 + kg;
#pragma unroll
    for (int f = 0; f < 4; f++){
      int m = wm * 64 + f * 16 + ln;
      aoff[ks][f] = m * 128 + (((qs ^ (ln & 7)) & 7) << 4);
    }
#pragma unroll
    for (int f = 0; f < 2; f++){
      int n = wn * 32 + f * 16 + ln;
      boff[ks][f] = n * 128 + (((qs ^ swzB(n)) & 7) << 4);
    }
  }

  f4 accg[4][2], accu[4][2];
#pragma unroll
  for (int a = 0; a < 4; a++)
#pragma unroll
    for (int b = 0; b < 2; b++){ accg[a][b] = f4{0,0,0,0}; accu[a][b] = f4{0,0,0,0}; }

  // ---- prologue: queue = B(0)x8, A(0)x4, B(1)x8 ----
  f4 bg[2][4], bu[2][4];
  { const f4* p = (const f4*)gsrc;
    bg[0][0] = p[0]; bg[0][1] = p[ID/4]; bg[0][2] = p[ID/2]; bg[0][3] = p[3*ID/4];
    const f4* q = (const f4*)usrc;
    bu[0][0] = q[0]; bu[0][1] = q[ID/4]; bu[0][2] = q[ID/2]; bu[0][3] = q[3*ID/4]; }
  __builtin_amdgcn_sched_barrier(0);
#pragma unroll
  for (int i = 0; i < 4; i++) glds16(asrc[i], &sA[0][0] + wid * 4096 + i * 1024);
  __builtin_amdgcn_sched_barrier(0);
  { const f4* p = (const f4*)(gsrc + (size_t)64 * ID);
    bg[1][0] = p[0]; bg[1][1] = p[ID/4]; bg[1][2] = p[ID/2]; bg[1][3] = p[3*ID/4];
    const f4* q = (const f4*)(usrc + (size_t)64 * ID);
    bu[1][0] = q[0]; bu[1][1] = q[ID/4]; bu[1][2] = q[ID/2]; bu[1][3] = q[3*ID/4]; }
  __builtin_amdgcn_sched_barrier(0);

  for (int it = 0; it < 16; ++it){
#pragma unroll
    for (int par = 0; par < 2; ++par){
      const int kt = it * 2 + par;
      // bar1: all waves done reading LDS of previous iteration
      asm volatile("s_waitcnt lgkmcnt(0)" ::: "memory");
      __builtin_amdgcn_s_barrier();
      __builtin_amdgcn_sched_barrier(0);
      // R1: glds A(kt+1) -> other buffer
      { const int kc1 = kt + 1 < 32 ? kt + 1 : 31;
        char* dst = &sA[par ^ 1][0] + wid * 4096;
#pragma unroll
        for (int i = 0; i < 4; i++) glds16(asrc[i] + (size_t)kc1 * 128, dst + i * 1024);
      }
      __builtin_amdgcn_sched_barrier(0);
      // R2: ds_write B(kt) (regs loaded 2 iters ago; compiler inserts exact counted vmcnt),
      //     then issue B(kt+2) loads into the same regset
#pragma unroll
      for (int j = 0; j < 4; j++){
        *(uint2*)(sBg + bw[j]) = uint2{ pk2(bg[par][0][j], bg[par][1][j]),
                                        pk2(bg[par][2][j], bg[par][3][j]) };
        *(uint2*)(sBu + bw[j]) = uint2{ pk2(bu[par][0][j], bu[par][1][j]),
                                        pk2(bu[par][2][j], bu[par][3][j]) };
      }
      { const int kc2 = kt + 2 < 32 ? kt + 2 : 31;
        const f4* p = (const f4*)(gsrc + (size_t)kc2 * 64 * ID);
        bg[par][0] = p[0]; bg[par][1] = p[ID/4]; bg[par][2] = p[ID/2]; bg[par][3] = p[3*ID/4];
        const f4* q = (const f4*)(usrc + (size_t)kc2 * 64 * ID);
        bu[par][0] = q[0]; bu[par][1] = q[ID/4]; bu[par][2] = q[ID/2]; bu[par][3] = q[3*ID/4]; }
      __builtin_amdgcn_sched_barrier(0);
      // bar2: drain ONLY A(kt) glds (leave B(kt+1),A(kt+1),B(kt+2) = 20 in flight)
      asm volatile("s_waitcnt vmcnt(20) lgkmcnt(0)" ::: "memory");
      __builtin_amdgcn_s_barrier();
      __builtin_amdgcn_sched_barrier(0);
      // compute from buf par
      const char* A = &sA[par][0];
#pragma unroll
      for (int ks = 0; ks < 2; ks++){
        short8 af[4];
#pragma unroll
        for (int f = 0; f < 4; f++) af[f] = *(const short8*)(A + aoff[ks][f]);
#pragma unroll
        for (int fn = 0; fn < 2; fn++){
          short8 sg = *(const short8*)(sBg + boff[ks][fn]);
          short8 su = *(const short8*)(sBu + boff[ks][fn]);
#pragma unroll
          for (int fm = 0; fm < 4; fm++){
            accg[fm][fn] = __builtin_amdgcn_mfma_f32_16x16x32_bf16(af[fm], sg, accg[fm][fn], 0, 0, 0);
            accu[fm][fn] = __builtin_amdgcn_mfma_f32_16x16x32_bf16(af[fm], su, accu[fm][fn], 0, 0, 0);
          }
        }
      }
    }
  }
  // epilogue: h = gelu(g)*u -> bf16
#pragma unroll
  for (int fm = 0; fm < 4; fm++){
#pragma unroll
    for (int r = 0; r < 4; r++){
      int row = wm * 64 + fm * 16 + (lane >> 4) * 4 + r;
      if (row < cntL){
        size_t base = (size_t)(p0 + row) * ID + (size_t)nt * 64 + wn * 32 + ln;
#pragma unroll
        for (int fn = 0; fn < 2; fn++){
          float g = accg[fm][fn][r];
          float u = accu[fm][fn][r];
          hbuf[base + fn * 16] = __float2bfloat16(gelu_t(g) * u);
        }
      }
    }
  }
}

// -------- down GEMM + weighted atomic scatter: 128(m) x 128(n), BK=64, depth-2 pipeline --------
__global__ __launch_bounds__(256, 3)
void k_down(const __hip_bfloat16* __restrict__ hbuf, const float* __restrict__ Wd,
            const int* __restrict__ row_tok, const float* __restrict__ row_w,
            const int* __restrict__ off, float* __restrict__ out){
  __shared__ __align__(16) char sA[2][16384];   // [128 m][64 k] bf16
  __shared__ __align__(16) char sB[16384];      // [128 n][64 k] bf16
  __shared__ int s_tok[128];
  __shared__ float s_w[128];

  const int bid = blockIdx.x;           // 1024 = 8e x 8mt x 16nt
  const int e  = bid & 7;
  const int mt = (bid >> 3) & 7;
  const int nt = bid >> 6;              // 0..15
  const int o0 = off[e], cnt = off[e + 1] - o0;
  if (mt * 128 >= cnt) return;
  const int p0 = o0 + mt * 128;
  const int cntL = min(128, cnt - mt * 128);
  const int tid = threadIdx.x;
  const int wid = tid >> 6, lane = tid & 63;

  if (tid < 128){
    int p = min(p0 + tid, TT*2 - 1);
    s_tok[tid] = row_tok[p];
    s_w[tid]   = row_w[p];
  }
  __syncthreads();

  const char* asrc[4];
#pragma unroll
  for (int i = 0; i < 4; i++){
    int c = wid * 4 + i;
    int r = c * 8 + (lane >> 3);
    int p = min(p0 + r, TT*2 - 1);
    asrc[i] = (const char*)hbuf + (size_t)p * (ID * 2)
            + ((((lane & 7) ^ (lane >> 3)) & 7) << 4);
  }
  // B staging: thread -> 8 k-rows x 4 n
  const int n0 = (tid & 31) * 4;
  const int k0 = (tid >> 5) * 8;        // 0..56
  const float* bsrc = Wd + (size_t)e * ID * HD + (size_t)k0 * HD + (size_t)nt * 128 + n0;
  int bw[4];
#pragma unroll
  for (int j = 0; j < 4; j++)
    bw[j] = (n0 + j) * 128 + ((((k0 >> 3) ^ (tid & 7) ^ (j << 1)) & 7) << 4);

  const int wm = wid >> 1, wn = wid & 1;     // 2x2 waves: 64 x 64
  const int kg = lane >> 4, ln = lane & 15;
  int aoff[2][4], boff[2][4];
#pragma unroll
  for (int ks = 0; ks < 2; ks++){
    int qs = ks * 4 + kg;
#pragma unroll
    for (int f = 0; f < 4; f++){
      int m = wm * 64 + f * 16 + ln;
      aoff[ks][f] = m * 128 + (((qs ^ (ln & 7)) & 7) << 4);
      int n = wn * 64 + f * 16 + ln;
      boff[ks][f] = n * 128 + (((qs ^ swzB(n)) & 7) << 4);
    }
  }

  f4 acc[4][4];
#pragma unroll
  for (int a = 0; a < 4; a++)
#pragma unroll
    for (int b = 0; b < 4; b++) acc[a][b] = f4{0,0,0,0};

  // prologue: queue = B(0)x8, A(0)x4, B(1)x8
  f4 bd[2][8];
  { const f4* p = (const f4*)bsrc;
#pragma unroll
    for (int r = 0; r < 8; r++) bd[0][r] = p[r * (HD/4)]; }
  __builtin_amdgcn_sched_barrier(0);
#pragma unroll
  for (int i = 0; i < 4; i++) glds16(asrc[i], &sA[0][0] + wid * 4096 + i * 1024);
  __builtin_amdgcn_sched_barrier(0);
  { const f4* p = (const f4*)(bsrc + (size_t)64 * HD);
#pragma unroll
    for (int r = 0; r < 8; r++) bd[1][r] = p[r * (HD/4)]; }
  __builtin_amdgcn_sched_barrier(0);

  for (int it = 0; it < 16; ++it){
#pragma unroll
    for (int par = 0; par < 2; ++par){
      const int kt = it * 2 + par;
      asm volatile("s_waitcnt lgkmcnt(0)" ::: "memory");
      __builtin_amdgcn_s_barrier();
      __builtin_amdgcn_sched_barrier(0);
      { const int kc1 = kt + 1 < 32 ? kt + 1 : 31;
        char* dst = &sA[par ^ 1][0] + wid * 4096;
#pragma unroll
        for (int i = 0; i < 4; i++) glds16(asrc[i] + (size_t)kc1 * 128, dst + i * 1024);
      }
      __builtin_amdgcn_sched_barrier(0);
#pragma unroll
      for (int j = 0; j < 4; j++){
        *(uint4*)(sB + bw[j]) = uint4{ pk2(bd[par][0][j], bd[par][1][j]),
                                       pk2(bd[par][2][j], bd[par][3][j]),
                                       pk2(bd[par][4][j], bd[par][5][j]),
                                       pk2(bd[par][6][j], bd[par][7][j]) };
      }
      { const int kc2 = kt + 2 < 32 ? kt + 2 : 31;
        const f4* p = (const f4*)(bsrc + (size_t)kc2 * 64 * HD);
#pragma unroll
        for (int r = 0; r < 8; r++) bd[par][r] = p[r * (HD/4)]; }
      __builtin_amdgcn_sched_barrier(0);
      asm volatile("s_waitcnt vmcnt(20) lgkmcnt(0)" ::: "memory");
      __builtin_amdgcn_s_barrier();
      __builtin_amdgcn_sched_barrier(0);
      const char* A = &sA[par][0];
#pragma unroll
      for (int ks = 0; ks < 2; ks++){
        short8 af[4];
#pragma unroll
        for (int f = 0; f < 4; f++) af[f] = *(const short8*)(A + aoff[ks][f]);
#pragma unroll
        for (int fn = 0; fn < 4; fn++){
          short8 bf = *(const short8*)(sB + boff[ks][fn]);
#pragma unroll
          for (int fm = 0; fm < 4; fm++)
            acc[fm][fn] = __builtin_amdgcn_mfma_f32_16x16x32_bf16(af[fm], bf, acc[fm][fn], 0, 0, 0);
        }
      }
    }
  }
  // epilogue: out[tok] += w * y   (2 commutative fp32 adds per element, deterministic)
#pragma unroll
  for (int fm = 0; fm < 4; fm++){
#pragma unroll
    for (int r = 0; r < 4; r++){
      int row = wm * 64 + fm * 16 + (lane >> 4) * 4 + r;
      if (row < cntL){
        int tok = s_tok[row];
        float w = s_w[row];
        float* ob = out + (size_t)tok * HD + (size_t)nt * 128 + wn * 64 + ln;
#pragma unroll
        for (int fn = 0; fn < 4; fn++)
          atomicAdd(ob + fn * 16, acc[fm][fn][r] * w);
      }
    }
  }
}

extern "C" void kernel_launch(void* const* d_in, const int* in_sizes, int n_in,
                              void* d_out, int out_size, void* d_ws, size_t ws_size,
                              hipStream_t stream){
  (void)in_sizes; (void)n_in; (void)out_size; (void)ws_size;
  const float* X  = (const float*)d_in[0];
  const float* RL = (const float*)d_in[1];
  const float* SC = (const float*)d_in[2];
  const float* Wg = (const float*)d_in[3];
  const float* Wu = (const float*)d_in[4];
  const float* Wd = (const float*)d_in[5];
  float* out = (float*)d_out;

  char* ws = (char*)d_ws;
  int*   rid     = (int*)(ws);
  float* rw      = (float*)(ws + 16384);
  int*   row_tok = (int*)(ws + 32768);
  float* row_w   = (float*)(ws + 49152);
  int*   off     = (int*)(ws + 65536);
  __hip_bfloat16* hbuf = (__hip_bfloat16*)(ws + 66560);                      // 16 MiB
  __hip_bfloat16* Xb   = (__hip_bfloat16*)(ws + 66560 + (size_t)TT*2*ID*2);  // 8 MiB

  hipMemsetAsync(d_out, 0, (size_t)TT * HD * sizeof(float), stream);
  k_cvtx <<<2048, 256, 0, stream>>>(X, Xb);
  k_route<<<TT / 256, 256, 0, stream>>>(RL, SC, rid, rw);
  k_lists<<<1, 64, 0, stream>>>(rid, rw, row_tok, row_w, off);
  k_gateup<<<2048, 256, 0, stream>>>(Xb, Wg, Wu, row_tok, off, hbuf);
  k_down<<<1024, 256, 0, stream>>>(hbuf, Wd, row_tok, row_w, off, out);
}

// Round 5
// 465.005 us; speedup vs baseline: 2.0648x; 2.0648x over previous
//
#include <hip/hip_runtime.h>
#include <hip/hip_bf16.h>

#define TT 2048
#define HD 2048
#define ID 2048
#define NE 8

typedef __attribute__((ext_vector_type(8))) short short8;
typedef __attribute__((ext_vector_type(4))) float f4;

__device__ __forceinline__ unsigned short b16(float f){
  union { __hip_bfloat16 b; unsigned short u; } x;
  x.b = __float2bfloat16(f);
  return x.u;
}
__device__ __forceinline__ unsigned pk2(float lo, float hi){
  return (unsigned)b16(lo) | ((unsigned)b16(hi) << 16);
}
__device__ __forceinline__ float gelu_t(float x){
  float y = 0.7978845608028654f * (x + 0.044715f * x * x * x);
  float t = 1.0f - 2.0f / (__expf(2.0f * y) + 1.0f);
  return 0.5f * x * (1.0f + t);
}
__device__ __forceinline__ void glds16(const void* g, void* l){
  __builtin_amdgcn_global_load_lds(
      (const __attribute__((address_space(1))) unsigned*)g,
      (__attribute__((address_space(3))) unsigned*)l, 16, 0, 0);
}
__device__ __forceinline__ void softbar(){
  asm volatile("s_waitcnt lgkmcnt(0)" ::: "memory");
  __builtin_amdgcn_s_barrier();
  __builtin_amdgcn_sched_barrier(0);
}
__device__ __forceinline__ void hardbar(){
  asm volatile("s_waitcnt vmcnt(0)" ::: "memory");
  __builtin_amdgcn_s_barrier();
  __builtin_amdgcn_sched_barrier(0);
}
__device__ __forceinline__ int swzB(int n){ return (((n >> 2) & 7) ^ ((n & 3) << 1)) & 7; }

// ---------------- X fp32 -> bf16 ----------------
__global__ void k_cvtx(const float* __restrict__ X, __hip_bfloat16* __restrict__ Xb){
  int i = blockIdx.x * 256 + threadIdx.x;
  const f4* src = (const f4*)X + (size_t)i * 2;
  f4 a = src[0], b = src[1];
  uint4 o = { pk2(a[0],a[1]), pk2(a[2],a[3]), pk2(b[0],b[1]), pk2(b[2],b[3]) };
  ((uint4*)Xb)[i] = o;
}

// -------- W fp32 [e][k][n] -> bf16 [e][n][k] (transpose-convert), tile 128k x 64n --------
__global__ __launch_bounds__(256)
void k_cvtw(const float* __restrict__ Wg, const float* __restrict__ Wu,
            const float* __restrict__ Wd, __hip_bfloat16* __restrict__ Wb){
  __shared__ float s_t[128 * 65];
  const int bid = blockIdx.x;                 // 3 x 8 x 16kt x 32nt = 12288
  const int nt = bid & 31;
  const int kt = (bid >> 5) & 15;
  const int e  = (bid >> 9) & 7;
  const int m  = bid >> 12;
  const float* S = (m == 0 ? Wg : (m == 1 ? Wu : Wd))
                 + (size_t)e * HD * ID + (size_t)(kt * 128) * 2048 + nt * 64;
  __hip_bfloat16* D = Wb + (size_t)m * ((size_t)NE * 2048 * 2048)
                    + (size_t)(e * 2048 + nt * 64) * 2048 + kt * 128;
  const int tid = threadIdx.x;
  const int col4 = tid & 15, rq = tid >> 4;   // rq 0..15
#pragma unroll
  for (int i = 0; i < 8; i++){
    int row = i * 16 + rq;
    f4 v = *(const f4*)(S + (size_t)row * 2048 + col4 * 4);
#pragma unroll
    for (int j = 0; j < 4; j++) s_t[row * 65 + col4 * 4 + j] = v[j];
  }
  __syncthreads();
  const int n = tid & 63, kq = (tid >> 6) * 32;
  unsigned o[16];
#pragma unroll
  for (int a = 0; a < 16; a++){
    float lo = s_t[(kq + a * 2) * 65 + n];
    float hi = s_t[(kq + a * 2 + 1) * 65 + n];
    o[a] = pk2(lo, hi);
  }
  char* dp = (char*)(D + (size_t)n * 2048 + kq);
#pragma unroll
  for (int a = 0; a < 4; a++)
    *(uint4*)(dp + a * 16) = uint4{ o[a*4], o[a*4+1], o[a*4+2], o[a*4+3] };
}

// ---------------- routing ----------------
__global__ void k_route(const float* __restrict__ lg, const float* __restrict__ sc,
                        int* __restrict__ rid, float* __restrict__ rw){
  int t = blockIdx.x * blockDim.x + threadIdx.x;
  if (t >= TT) return;
  float l[NE];
#pragma unroll
  for (int e = 0; e < NE; e++) l[e] = lg[t * NE + e];
  float mx = l[0];
#pragma unroll
  for (int e = 1; e < NE; e++) mx = fmaxf(mx, l[e]);
  float p[NE];
#pragma unroll
  for (int e = 0; e < NE; e++) p[e] = __expf(l[e] - mx);
  int i0 = 0; float b0 = l[0];
#pragma unroll
  for (int e = 1; e < NE; e++) if (l[e] > b0){ b0 = l[e]; i0 = e; }
  int i1 = -1; float b1 = -1e30f;
#pragma unroll
  for (int e = 0; e < NE; e++) if (e != i0 && l[e] > b1){ b1 = l[e]; i1 = e; }
  float p0 = p[i0], p1 = p[i1];
  float rn = p0 + p1; rn = (rn > 0.f) ? rn : 1.f;
  rw[t*2]   = p0 / rn * sc[i0];
  rw[t*2+1] = p1 / rn * sc[i1];
  rid[t*2]  = i0;
  rid[t*2+1]= i1;
}

// ---------------- deterministic per-expert compaction ----------------
__global__ void k_lists(const int* __restrict__ rid, const float* __restrict__ rw,
                        int* __restrict__ row_tok, float* __restrict__ row_w,
                        int* __restrict__ off){
  int lane = threadIdx.x;            // 64 threads
  int ids[64]; float wv[64];
#pragma unroll
  for (int i = 0; i < 64; i++) ids[i] = rid[i * 64 + lane];
#pragma unroll
  for (int i = 0; i < 64; i++) wv[i] = rw[i * 64 + lane];
  int cnt[NE];
#pragma unroll
  for (int e = 0; e < NE; e++) cnt[e] = 0;
#pragma unroll
  for (int i = 0; i < 64; i++){
#pragma unroll
    for (int e = 0; e < NE; e++)
      cnt[e] += __popcll(__ballot(ids[i] == e));
  }
  int offs[NE + 1]; offs[0] = 0;
#pragma unroll
  for (int e = 0; e < NE; e++) offs[e + 1] = offs[e] + cnt[e];
  if (lane == 0){
#pragma unroll
    for (int e = 0; e <= NE; e++) off[e] = offs[e];
  }
  int run[NE];
#pragma unroll
  for (int e = 0; e < NE; e++) run[e] = offs[e];
  unsigned long long ltm = (1ULL << lane) - 1ULL;
#pragma unroll
  for (int i = 0; i < 64; i++){
    int id = ids[i];
    int tok = (i * 64 + lane) >> 1;
#pragma unroll
    for (int e = 0; e < NE; e++){
      unsigned long long m = __ballot(id == e);
      if (id == e){
        int pos = run[e] + __popcll(m & ltm);
        row_tok[pos] = tok;
        row_w[pos]   = wv[i];
      }
      run[e] += __popcll(m);
    }
  }
}

// ================= FAST PATH: all-glds 2-phase pipeline (no ds_write in loop) =================

// -------- gate+up: 128m x 64n dual tile, BK=64, both operands glds-staged --------
__global__ __launch_bounds__(256, 2)
void k_gateup_f(const __hip_bfloat16* __restrict__ Xb, const __hip_bfloat16* __restrict__ Wtg,
                const __hip_bfloat16* __restrict__ Wtu, const int* __restrict__ row_tok,
                const int* __restrict__ off, __hip_bfloat16* __restrict__ hbuf){
  __shared__ __align__(16) char sA[2][16384];   // [128 m][64 k] bf16, slot^=(m&7)
  __shared__ __align__(16) char sBg[2][8192];   // [64 n][64 k] bf16, slot^=(n&7)
  __shared__ __align__(16) char sBu[2][8192];
  __shared__ int s_tok[128];

  const int bid = blockIdx.x;           // 2048 = 8e x 8mt x 32nt
  const int e  = bid & 7;
  const int mt = (bid >> 3) & 7;
  const int nt = bid >> 6;
  const int o0 = off[e], cnt = off[e + 1] - o0;
  if (mt * 128 >= cnt) return;
  const int p0 = o0 + mt * 128;
  const int cntL = min(128, cnt - mt * 128);
  const int tid = threadIdx.x;
  const int wid = tid >> 6, lane = tid & 63;

  if (tid < 128) s_tok[tid] = row_tok[min(p0 + tid, TT*2 - 1)];
  __syncthreads();

  const int lr = lane >> 3, ls = lane & 7;
  const int sw = ((ls ^ lr) & 7) << 4;          // inverse swizzle on source, linear dest
  const char* asrc[4];
#pragma unroll
  for (int i = 0; i < 4; i++){
    int r = (wid * 4 + i) * 8 + lr;
    asrc[i] = (const char*)Xb + (size_t)s_tok[r] * 4096 + sw;
  }
  const char* gsrc[2]; const char* usrc[2];
#pragma unroll
  for (int i = 0; i < 2; i++){
    int n = (wid * 2 + i) * 8 + lr;
    size_t rowb = (size_t)(e * 2048 + nt * 64 + n) * 4096;
    gsrc[i] = (const char*)Wtg + rowb + sw;
    usrc[i] = (const char*)Wtu + rowb + sw;
  }
  const int wm = wid >> 1, wn = wid & 1;        // 2x2 waves, each 64m x 32n (dual)
  const int kg = lane >> 4, ln = lane & 15;
  int aoff[2][4], boff[2][2];
#pragma unroll
  for (int ks = 0; ks < 2; ks++){
    int qs = ks * 4 + kg;
#pragma unroll
    for (int f = 0; f < 4; f++){
      int m = wm * 64 + f * 16 + ln;
      aoff[ks][f] = m * 128 + (((qs ^ (m & 7)) & 7) << 4);
    }
#pragma unroll
    for (int f = 0; f < 2; f++){
      int n = wn * 32 + f * 16 + ln;
      boff[ks][f] = n * 128 + (((qs ^ (n & 7)) & 7) << 4);
    }
  }

  f4 accg[4][2], accu[4][2];
#pragma unroll
  for (int a = 0; a < 4; a++)
#pragma unroll
    for (int b = 0; b < 2; b++){ accg[a][b] = f4{0,0,0,0}; accu[a][b] = f4{0,0,0,0}; }

#define GUSTAGE(buf, kt) do{ const int _o = (kt) * 128;                          \
    _Pragma("unroll") for (int i = 0; i < 4; i++)                                \
      glds16(asrc[i] + _o, &sA[buf][(wid * 4 + i) * 1024]);                      \
    _Pragma("unroll") for (int i = 0; i < 2; i++)                                \
      glds16(gsrc[i] + _o, &sBg[buf][(wid * 2 + i) * 1024]);                     \
    _Pragma("unroll") for (int i = 0; i < 2; i++)                                \
      glds16(usrc[i] + _o, &sBu[buf][(wid * 2 + i) * 1024]); }while(0)

  GUSTAGE(0, 0);
  hardbar();
  for (int kt = 0; kt < 32; ++kt){
    const int cur = kt & 1;
    if (kt + 1 < 32) GUSTAGE(cur ^ 1, kt + 1);
    __builtin_amdgcn_sched_barrier(0);
    const char* A = &sA[cur][0];
    const char* G = &sBg[cur][0];
    const char* U = &sBu[cur][0];
#pragma unroll
    for (int ks = 0; ks < 2; ks++){
      short8 af[4];
#pragma unroll
      for (int f = 0; f < 4; f++) af[f] = *(const short8*)(A + aoff[ks][f]);
#pragma unroll
      for (int fn = 0; fn < 2; fn++){
        short8 bg = *(const short8*)(G + boff[ks][fn]);
        short8 bu = *(const short8*)(U + boff[ks][fn]);
#pragma unroll
        for (int fm = 0; fm < 4; fm++){
          accg[fm][fn] = __builtin_amdgcn_mfma_f32_16x16x32_bf16(af[fm], bg, accg[fm][fn], 0, 0, 0);
          accu[fm][fn] = __builtin_amdgcn_mfma_f32_16x16x32_bf16(af[fm], bu, accu[fm][fn], 0, 0, 0);
        }
      }
    }
    __builtin_amdgcn_sched_barrier(0);
    hardbar();                                  // drain prefetch (covered by compute), sync
  }
#undef GUSTAGE
  // epilogue: h = gelu(g)*u -> bf16
#pragma unroll
  for (int fm = 0; fm < 4; fm++){
#pragma unroll
    for (int r = 0; r < 4; r++){
      int row = wm * 64 + fm * 16 + (lane >> 4) * 4 + r;
      if (row < cntL){
        size_t base = (size_t)(p0 + row) * ID + (size_t)nt * 64 + wn * 32 + ln;
#pragma unroll
        for (int fn = 0; fn < 2; fn++){
          float g = accg[fm][fn][r];
          float u = accu[fm][fn][r];
          hbuf[base + fn * 16] = __float2bfloat16(gelu_t(g) * u);
        }
      }
    }
  }
}

// -------- down: 128m x 128n, BK=64, both operands glds-staged + weighted atomic scatter --------
__global__ __launch_bounds__(256, 2)
void k_down_f(const __hip_bfloat16* __restrict__ hbuf, const __hip_bfloat16* __restrict__ Wtd,
              const int* __restrict__ row_tok, const float* __restrict__ row_w,
              const int* __restrict__ off, float* __restrict__ out){
  __shared__ __align__(16) char sA[2][16384];   // [128 m][64 k]
  __shared__ __align__(16) char sB[2][16384];   // [128 n][64 k]
  __shared__ int s_tok[128];
  __shared__ float s_w[128];

  const int bid = blockIdx.x;           // 1024 = 8e x 8mt x 16nt
  const int e  = bid & 7;
  const int mt = (bid >> 3) & 7;
  const int nt = bid >> 6;
  const int o0 = off[e], cnt = off[e + 1] - o0;
  if (mt * 128 >= cnt) return;
  const int p0 = o0 + mt * 128;
  const int cntL = min(128, cnt - mt * 128);
  const int tid = threadIdx.x;
  const int wid = tid >> 6, lane = tid & 63;

  if (tid < 128){
    int p = min(p0 + tid, TT*2 - 1);
    s_tok[tid] = row_tok[p];
    s_w[tid]   = row_w[p];
  }
  __syncthreads();

  const int lr = lane >> 3, ls = lane & 7;
  const int sw = ((ls ^ lr) & 7) << 4;
  const char* asrc[4]; const char* bsrc[4];
#pragma unroll
  for (int i = 0; i < 4; i++){
    int r = (wid * 4 + i) * 8 + lr;
    int p = min(p0 + r, TT*2 - 1);
    asrc[i] = (const char*)hbuf + (size_t)p * 4096 + sw;
    bsrc[i] = (const char*)Wtd + (size_t)(e * 2048 + nt * 128 + r) * 4096 + sw;
  }
  const int wm = wid >> 1, wn = wid & 1;        // 2x2 waves: 64 x 64
  const int kg = lane >> 4, ln = lane & 15;
  int aoff[2][4], boff[2][4];
#pragma unroll
  for (int ks = 0; ks < 2; ks++){
    int qs = ks * 4 + kg;
#pragma unroll
    for (int f = 0; f < 4; f++){
      int m = wm * 64 + f * 16 + ln;
      aoff[ks][f] = m * 128 + (((qs ^ (m & 7)) & 7) << 4);
      int n = wn * 64 + f * 16 + ln;
      boff[ks][f] = n * 128 + (((qs ^ (n & 7)) & 7) << 4);
    }
  }

  f4 acc[4][4];
#pragma unroll
  for (int a = 0; a < 4; a++)
#pragma unroll
    for (int b = 0; b < 4; b++) acc[a][b] = f4{0,0,0,0};

#define DSTAGE(buf, kt) do{ const int _o = (kt) * 128;                           \
    _Pragma("unroll") for (int i = 0; i < 4; i++)                                \
      glds16(asrc[i] + _o, &sA[buf][(wid * 4 + i) * 1024]);                      \
    _Pragma("unroll") for (int i = 0; i < 4; i++)                                \
      glds16(bsrc[i] + _o, &sB[buf][(wid * 4 + i) * 1024]); }while(0)

  DSTAGE(0, 0);
  hardbar();
  for (int kt = 0; kt < 32; ++kt){
    const int cur = kt & 1;
    if (kt + 1 < 32) DSTAGE(cur ^ 1, kt + 1);
    __builtin_amdgcn_sched_barrier(0);
    const char* A = &sA[cur][0];
    const char* B = &sB[cur][0];
#pragma unroll
    for (int ks = 0; ks < 2; ks++){
      short8 af[4];
#pragma unroll
      for (int f = 0; f < 4; f++) af[f] = *(const short8*)(A + aoff[ks][f]);
#pragma unroll
      for (int fn = 0; fn < 4; fn++){
        short8 bf = *(const short8*)(B + boff[ks][fn]);
#pragma unroll
        for (int fm = 0; fm < 4; fm++)
          acc[fm][fn] = __builtin_amdgcn_mfma_f32_16x16x32_bf16(af[fm], bf, acc[fm][fn], 0, 0, 0);
      }
    }
    __builtin_amdgcn_sched_barrier(0);
    hardbar();
  }
#undef DSTAGE
#pragma unroll
  for (int fm = 0; fm < 4; fm++){
#pragma unroll
    for (int r = 0; r < 4; r++){
      int row = wm * 64 + fm * 16 + (lane >> 4) * 4 + r;
      if (row < cntL){
        int tok = s_tok[row];
        float w = s_w[row];
        float* ob = out + (size_t)tok * HD + (size_t)nt * 128 + wn * 64 + ln;
#pragma unroll
        for (int fn = 0; fn < 4; fn++)
          atomicAdd(ob + fn * 16, acc[fm][fn][r] * w);
      }
    }
  }
}

// ================= FALLBACK PATH (round-3 kernels, known-good) =================

__global__ __launch_bounds__(256, 3)
void k_gateup_r3(const __hip_bfloat16* __restrict__ Xb, const float* __restrict__ Wg,
                 const float* __restrict__ Wu, const int* __restrict__ row_tok,
                 const int* __restrict__ off, __hip_bfloat16* __restrict__ hbuf){
  __shared__ __align__(16) char sA[2][16384];
  __shared__ __align__(16) char sBg[8192];
  __shared__ __align__(16) char sBu[8192];
  __shared__ int s_tok[128];

  const int bid = blockIdx.x;
  const int e  = bid & 7;
  const int mt = (bid >> 3) & 7;
  const int nt = bid >> 6;
  const int o0 = off[e], cnt = off[e + 1] - o0;
  if (mt * 128 >= cnt) return;
  const int p0 = o0 + mt * 128;
  const int cntL = min(128, cnt - mt * 128);
  const int tid = threadIdx.x;
  const int wid = tid >> 6, lane = tid & 63;

  if (tid < 128) s_tok[tid] = row_tok[min(p0 + tid, TT*2 - 1)];
  __syncthreads();

  const char* asrc[4];
#pragma unroll
  for (int i = 0; i < 4; i++){
    int c = wid * 4 + i;
    int r = c * 8 + (lane >> 3);
    asrc[i] = (const char*)Xb + (size_t)s_tok[r] * (HD * 2)
            + ((((lane & 7) ^ (lane >> 3)) & 7) << 4);
  }
  const int n0 = (tid & 15) * 4;
  const int k0 = (tid >> 4) * 4;
  const size_t wb = (size_t)e * HD * ID + (size_t)k0 * ID + (size_t)nt * 64 + n0;
  const float* gsrc = Wg + wb;
  const float* usrc = Wu + wb;
  int bw[4];
#pragma unroll
  for (int j = 0; j < 4; j++)
    bw[j] = (n0 + j) * 128 + ((((k0 >> 3) ^ (tid & 7) ^ (j << 1)) & 7) << 4) + ((k0 & 4) << 1);

  const int wm = wid >> 1, wn = wid & 1;
  const int kg = lane >> 4, ln = lane & 15;
  int aoff[2][4], boff[2][2];
#pragma unroll
  for (int ks = 0; ks < 2; ks++){
    int qs = ks * 4 + kg;
#pragma unroll
    for (int f = 0; f < 4; f++){
      int m = wm * 64 + f * 16 + ln;
      aoff[ks][f] = m * 128 + (((qs ^ (ln & 7)) & 7) << 4);
    }
#pragma unroll
    for (int f = 0; f < 2; f++){
      int n = wn * 32 + f * 16 + ln;
      boff[ks][f] = n * 128 + (((qs ^ swzB(n)) & 7) << 4);
    }
  }

  f4 accg[4][2], accu[4][2];
#pragma unroll
  for (int a = 0; a < 4; a++)
#pragma unroll
    for (int b = 0; b < 2; b++){ accg[a][b] = f4{0,0,0,0}; accu[a][b] = f4{0,0,0,0}; }

#pragma unroll
  for (int i = 0; i < 4; i++) glds16(asrc[i], &sA[0][(wid * 4 + i) * 1024]);
  f4 g0, g1, g2, g3, u0, u1, u2, u3;
  { const f4* p = (const f4*)gsrc; g0 = p[0]; g1 = p[ID/4]; g2 = p[ID/2]; g3 = p[3*ID/4];
    const f4* q = (const f4*)usrc; u0 = q[0]; u1 = q[ID/4]; u2 = q[ID/2]; u3 = q[3*ID/4]; }

  for (int kt = 0; kt < 32; ++kt){
    softbar();
    if (kt + 1 < 32){
      char* dst = &sA[(kt + 1) & 1][0] + (wid * 4) * 1024;
#pragma unroll
      for (int i = 0; i < 4; i++) glds16(asrc[i] + (size_t)(kt + 1) * 128, dst + i * 1024);
    }
#pragma unroll
    for (int j = 0; j < 4; j++){
      *(uint2*)(sBg + bw[j]) = uint2{ pk2(g0[j], g1[j]), pk2(g2[j], g3[j]) };
      *(uint2*)(sBu + bw[j]) = uint2{ pk2(u0[j], u1[j]), pk2(u2[j], u3[j]) };
    }
    softbar();
    if (kt + 1 < 32){
      const f4* p = (const f4*)(gsrc + (size_t)(kt + 1) * 64 * ID);
      g0 = p[0]; g1 = p[ID/4]; g2 = p[ID/2]; g3 = p[3*ID/4];
      const f4* q = (const f4*)(usrc + (size_t)(kt + 1) * 64 * ID);
      u0 = q[0]; u1 = q[ID/4]; u2 = q[ID/2]; u3 = q[3*ID/4];
    }
    const char* A = &sA[kt & 1][0];
#pragma unroll
    for (int ks = 0; ks < 2; ks++){
      short8 af[4];
#pragma unroll
      for (int f = 0; f < 4; f++) af[f] = *(const short8*)(A + aoff[ks][f]);
#pragma unroll
      for (int fn = 0; fn < 2; fn++){
        short8 bg = *(const short8*)(sBg + boff[ks][fn]);
        short8 bu = *(const short8*)(sBu + boff[ks][fn]);
#pragma unroll
        for (int fm = 0; fm < 4; fm++){
          accg[fm][fn] = __builtin_amdgcn_mfma_f32_16x16x32_bf16(af[fm], bg, accg[fm][fn], 0, 0, 0);
          accu[fm][fn] = __builtin_amdgcn_mfma_f32_16x16x32_bf16(af[fm], bu, accu[fm][fn], 0, 0, 0);
        }
      }
    }
  }
#pragma unroll
  for (int fm = 0; fm < 4; fm++){
#pragma unroll
    for (int r = 0; r < 4; r++){
      int row = wm * 64 + fm * 16 + (lane >> 4) * 4 + r;
      if (row < cntL){
        size_t base = (size_t)(p0 + row) * ID + (size_t)nt * 64 + wn * 32 + ln;
#pragma unroll
        for (int fn = 0; fn < 2; fn++){
          float g = accg[fm][fn][r];
          float u = accu[fm][fn][r];
          hbuf[base + fn * 16] = __float2bfloat16(gelu_t(g) * u);
        }
      }
    }
  }
}

__global__ __launch_bounds__(256, 3)
void k_down_r3(const __hip_bfloat16* __restrict__ hbuf, const float* __restrict__ Wd,
               const int* __restrict__ row_tok, const float* __restrict__ row_w,
               const int* __restrict__ off, float* __restrict__ out){
  __shared__ __align__(16) char sA[2][16384];
  __shared__ __align__(16) char sB[16384];
  __shared__ int s_tok[128];
  __shared__ float s_w[128];

  const int bid = blockIdx.x;
  const int e  = bid & 7;
  const int mt = (bid >> 3) & 7;
  const int nt = bid >> 6;
  const int o0 = off[e], cnt = off[e + 1] - o0;
  if (mt * 128 >= cnt) return;
  const int p0 = o0 + mt * 128;
  const int cntL = min(128, cnt - mt * 128);
  const int tid = threadIdx.x;
  const int wid = tid >> 6, lane = tid & 63;

  if (tid < 128){
    int p = min(p0 + tid, TT*2 - 1);
    s_tok[tid] = row_tok[p];
    s_w[tid]   = row_w[p];
  }
  __syncthreads();

  const char* asrc[4];
#pragma unroll
  for (int i = 0; i < 4; i++){
    int c = wid * 4 + i;
    int r = c * 8 + (lane >> 3);
    int p = min(p0 + r, TT*2 - 1);
    asrc[i] = (const char*)hbuf + (size_t)p * (ID * 2)
            + ((((lane & 7) ^ (lane >> 3)) & 7) << 4);
  }
  const int n0 = (tid & 31) * 4;
  const int k0 = (tid >> 5) * 8;
  const float* bsrc = Wd + (size_t)e * ID * HD + (size_t)k0 * HD + (size_t)nt * 128 + n0;
  int bw[4];
#pragma unroll
  for (int j = 0; j < 4; j++)
    bw[j] = (n0 + j) * 128 + ((((k0 >> 3) ^ (tid & 7) ^ (j << 1)) & 7) << 4);

  const int wm = wid >> 1, wn = wid & 1;
  const int kg = lane >> 4, ln = lane & 15;
  int aoff[2][4], boff[2][4];
#pragma unroll
  for (int ks = 0; ks < 2; ks++){
    int qs = ks * 4 + kg;
#pragma unroll
    for (int f = 0; f < 4; f++){
      int m = wm * 64 + f * 16 + ln;
      aoff[ks][f] = m * 128 + (((qs ^ (ln & 7)) & 7) << 4);
      int n = wn * 64 + f * 16 + ln;
      boff[ks][f] = n * 128 + (((qs ^ swzB(n)) & 7) << 4);
    }
  }

  f4 acc[4][4];
#pragma unroll
  for (int a = 0; a < 4; a++)
#pragma unroll
    for (int b = 0; b < 4; b++) acc[a][b] = f4{0,0,0,0};

#pragma unroll
  for (int i = 0; i < 4; i++) glds16(asrc[i], &sA[0][(wid * 4 + i) * 1024]);
  f4 r0, r1, r2, r3, r4, r5, r6, r7;
  { const f4* p = (const f4*)bsrc;
    r0 = p[0]; r1 = p[HD/4]; r2 = p[HD/2]; r3 = p[3*HD/4];
    r4 = p[HD]; r5 = p[5*HD/4]; r6 = p[3*HD/2]; r7 = p[7*HD/4]; }

  for (int kt = 0; kt < 32; ++kt){
    softbar();
    if (kt + 1 < 32){
      char* dst = &sA[(kt + 1) & 1][0] + (wid * 4) * 1024;
#pragma unroll
      for (int i = 0; i < 4; i++) glds16(asrc[i] + (size_t)(kt + 1) * 128, dst + i * 1024);
    }
#pragma unroll
    for (int j = 0; j < 4; j++){
      *(uint4*)(sB + bw[j]) = uint4{ pk2(r0[j], r1[j]), pk2(r2[j], r3[j]),
                                     pk2(r4[j], r5[j]), pk2(r6[j], r7[j]) };
    }
    softbar();
    if (kt + 1 < 32){
      const f4* p = (const f4*)(bsrc + (size_t)(kt + 1) * 64 * HD);
      r0 = p[0]; r1 = p[HD/4]; r2 = p[HD/2]; r3 = p[3*HD/4];
      r4 = p[HD]; r5 = p[5*HD/4]; r6 = p[3*HD/2]; r7 = p[7*HD/4];
    }
    const char* A = &sA[kt & 1][0];
#pragma unroll
    for (int ks = 0; ks < 2; ks++){
      short8 af[4];
#pragma unroll
      for (int f = 0; f < 4; f++) af[f] = *(const short8*)(A + aoff[ks][f]);
#pragma unroll
      for (int fn = 0; fn < 4; fn++){
        short8 bf = *(const short8*)(sB + boff[ks][fn]);
#pragma unroll
        for (int fm = 0; fm < 4; fm++)
          acc[fm][fn] = __builtin_amdgcn_mfma_f32_16x16x32_bf16(af[fm], bf, acc[fm][fn], 0, 0, 0);
      }
    }
  }
#pragma unroll
  for (int fm = 0; fm < 4; fm++){
#pragma unroll
    for (int r = 0; r < 4; r++){
      int row = wm * 64 + fm * 16 + (lane >> 4) * 4 + r;
      if (row < cntL){
        int tok = s_tok[row];
        float w = s_w[row];
        float* ob = out + (size_t)tok * HD + (size_t)nt * 128 + wn * 64 + ln;
#pragma unroll
        for (int fn = 0; fn < 4; fn++)
          atomicAdd(ob + fn * 16, acc[fm][fn][r] * w);
      }
    }
  }
}

extern "C" void kernel_launch(void* const* d_in, const int* in_sizes, int n_in,
                              void* d_out, int out_size, void* d_ws, size_t ws_size,
                              hipStream_t stream){
  (void)in_sizes; (void)n_in; (void)out_size;
  const float* X  = (const float*)d_in[0];
  const float* RL = (const float*)d_in[1];
  const float* SC = (const float*)d_in[2];
  const float* Wg = (const float*)d_in[3];
  const float* Wu = (const float*)d_in[4];
  const float* Wd = (const float*)d_in[5];
  float* out = (float*)d_out;

  char* ws = (char*)d_ws;
  int*   rid     = (int*)(ws);
  float* rw      = (float*)(ws + 16384);
  int*   row_tok = (int*)(ws + 32768);
  float* row_w   = (float*)(ws + 49152);
  int*   off     = (int*)(ws + 65536);
  __hip_bfloat16* hbuf = (__hip_bfloat16*)(ws + 66560);                      // 16 MiB
  __hip_bfloat16* Xb   = (__hip_bfloat16*)(ws + 66560 + 16777216ull);        // 8 MiB
  __hip_bfloat16* Wb   = (__hip_bfloat16*)(ws + 66560 + 16777216ull + 8388608ull);
  const size_t WME = (size_t)NE * 2048 * 2048;                               // elems per tensor
  const size_t need = 66560ull + 16777216ull + 8388608ull + 3ull * WME * 2ull;

  hipMemsetAsync(d_out, 0, (size_t)TT * HD * sizeof(float), stream);
  k_cvtx <<<2048, 256, 0, stream>>>(X, Xb);
  k_route<<<TT / 256, 256, 0, stream>>>(RL, SC, rid, rw);
  k_lists<<<1, 64, 0, stream>>>(rid, rw, row_tok, row_w, off);

  if (ws_size >= need){
    k_cvtw<<<12288, 256, 0, stream>>>(Wg, Wu, Wd, Wb);
    k_gateup_f<<<2048, 256, 0, stream>>>(Xb, Wb, Wb + WME, row_tok, off, hbuf);
    k_down_f  <<<1024, 256, 0, stream>>>(hbuf, Wb + 2 * WME, row_tok, row_w, off, out);
  } else {
    k_gateup_r3<<<2048, 256, 0, stream>>>(Xb, Wg, Wu, row_tok, off, hbuf);
    k_down_r3  <<<1024, 256, 0, stream>>>(hbuf, Wd, row_tok, row_w, off, out);
  }
}

// Round 6
// 463.708 us; speedup vs baseline: 2.0705x; 1.0028x over previous
//
#include <hip/hip_runtime.h>
#include <hip/hip_bf16.h>

#define TT 2048
#define HD 2048
#define ID 2048
#define NE 8

typedef __attribute__((ext_vector_type(8))) short short8;
typedef __attribute__((ext_vector_type(4))) float f4;

__device__ __forceinline__ unsigned short b16(float f){
  union { __hip_bfloat16 b; unsigned short u; } x;
  x.b = __float2bfloat16(f);
  return x.u;
}
__device__ __forceinline__ unsigned pk2(float lo, float hi){
  return (unsigned)b16(lo) | ((unsigned)b16(hi) << 16);
}
__device__ __forceinline__ float gelu_t(float x){
  float y = 0.7978845608028654f * (x + 0.044715f * x * x * x);
  float t = 1.0f - 2.0f / (__expf(2.0f * y) + 1.0f);
  return 0.5f * x * (1.0f + t);
}
__device__ __forceinline__ void glds16(const void* g, void* l){
  __builtin_amdgcn_global_load_lds(
      (const __attribute__((address_space(1))) unsigned*)g,
      (__attribute__((address_space(3))) unsigned*)l, 16, 0, 0);
}
__device__ __forceinline__ void softbar(){
  asm volatile("s_waitcnt lgkmcnt(0)" ::: "memory");
  __builtin_amdgcn_s_barrier();
  __builtin_amdgcn_sched_barrier(0);
}
__device__ __forceinline__ int swzB(int n){ return (((n >> 2) & 7) ^ ((n & 3) << 1)) & 7; }

// ---------------- X fp32 -> bf16 ----------------
__global__ void k_cvtx(const float* __restrict__ X, __hip_bfloat16* __restrict__ Xb){
  int i = blockIdx.x * 256 + threadIdx.x;
  const f4* src = (const f4*)X + (size_t)i * 2;
  f4 a = src[0], b = src[1];
  uint4 o = { pk2(a[0],a[1]), pk2(a[2],a[3]), pk2(b[0],b[1]), pk2(b[2],b[3]) };
  ((uint4*)Xb)[i] = o;
}

// -------- W fp32 [e][k][n] -> bf16 [e][n][k] (transpose-convert), tile 128k x 64n --------
__global__ __launch_bounds__(256)
void k_cvtw(const float* __restrict__ Wg, const float* __restrict__ Wu,
            const float* __restrict__ Wd, __hip_bfloat16* __restrict__ Wb){
  __shared__ float s_t[128 * 65];
  const int bid = blockIdx.x;                 // 3 x 8 x 16kt x 32nt = 12288
  const int nt = bid & 31;
  const int kt = (bid >> 5) & 15;
  const int e  = (bid >> 9) & 7;
  const int m  = bid >> 12;
  const float* S = (m == 0 ? Wg : (m == 1 ? Wu : Wd))
                 + (size_t)e * HD * ID + (size_t)(kt * 128) * 2048 + nt * 64;
  __hip_bfloat16* D = Wb + (size_t)m * ((size_t)NE * 2048 * 2048)
                    + (size_t)(e * 2048 + nt * 64) * 2048 + kt * 128;
  const int tid = threadIdx.x;
  const int col4 = tid & 15, rq = tid >> 4;   // rq 0..15
#pragma unroll
  for (int i = 0; i < 8; i++){
    int row = i * 16 + rq;
    f4 v = *(const f4*)(S + (size_t)row * 2048 + col4 * 4);
#pragma unroll
    for (int j = 0; j < 4; j++) s_t[row * 65 + col4 * 4 + j] = v[j];
  }
  __syncthreads();
  // write phase: 4 consecutive lanes cover one n-row's 128 k -> 256B contiguous stores
  const int n2 = tid >> 2, kc = (tid & 3) * 32;
  unsigned o[16];
#pragma unroll
  for (int a = 0; a < 16; a++){
    float lo = s_t[(kc + a * 2) * 65 + n2];
    float hi = s_t[(kc + a * 2 + 1) * 65 + n2];
    o[a] = pk2(lo, hi);
  }
  char* dp = (char*)(D + (size_t)n2 * 2048 + kc);
#pragma unroll
  for (int a = 0; a < 4; a++)
    *(uint4*)(dp + a * 16) = uint4{ o[a*4], o[a*4+1], o[a*4+2], o[a*4+3] };
}

// ---------------- routing ----------------
__global__ void k_route(const float* __restrict__ lg, const float* __restrict__ sc,
                        int* __restrict__ rid, float* __restrict__ rw){
  int t = blockIdx.x * blockDim.x + threadIdx.x;
  if (t >= TT) return;
  float l[NE];
#pragma unroll
  for (int e = 0; e < NE; e++) l[e] = lg[t * NE + e];
  float mx = l[0];
#pragma unroll
  for (int e = 1; e < NE; e++) mx = fmaxf(mx, l[e]);
  float p[NE];
#pragma unroll
  for (int e = 0; e < NE; e++) p[e] = __expf(l[e] - mx);
  int i0 = 0; float b0 = l[0];
#pragma unroll
  for (int e = 1; e < NE; e++) if (l[e] > b0){ b0 = l[e]; i0 = e; }
  int i1 = -1; float b1 = -1e30f;
#pragma unroll
  for (int e = 0; e < NE; e++) if (e != i0 && l[e] > b1){ b1 = l[e]; i1 = e; }
  float p0 = p[i0], p1 = p[i1];
  float rn = p0 + p1; rn = (rn > 0.f) ? rn : 1.f;
  rw[t*2]   = p0 / rn * sc[i0];
  rw[t*2+1] = p1 / rn * sc[i1];
  rid[t*2]  = i0;
  rid[t*2+1]= i1;
}

// ---------------- deterministic per-expert compaction ----------------
__global__ void k_lists(const int* __restrict__ rid, const float* __restrict__ rw,
                        int* __restrict__ row_tok, float* __restrict__ row_w,
                        int* __restrict__ off){
  int lane = threadIdx.x;            // 64 threads
  int ids[64]; float wv[64];
#pragma unroll
  for (int i = 0; i < 64; i++) ids[i] = rid[i * 64 + lane];
#pragma unroll
  for (int i = 0; i < 64; i++) wv[i] = rw[i * 64 + lane];
  int cnt[NE];
#pragma unroll
  for (int e = 0; e < NE; e++) cnt[e] = 0;
#pragma unroll
  for (int i = 0; i < 64; i++){
#pragma unroll
    for (int e = 0; e < NE; e++)
      cnt[e] += __popcll(__ballot(ids[i] == e));
  }
  int offs[NE + 1]; offs[0] = 0;
#pragma unroll
  for (int e = 0; e < NE; e++) offs[e + 1] = offs[e] + cnt[e];
  if (lane == 0){
#pragma unroll
    for (int e = 0; e <= NE; e++) off[e] = offs[e];
  }
  int run[NE];
#pragma unroll
  for (int e = 0; e < NE; e++) run[e] = offs[e];
  unsigned long long ltm = (1ULL << lane) - 1ULL;
#pragma unroll
  for (int i = 0; i < 64; i++){
    int id = ids[i];
    int tok = (i * 64 + lane) >> 1;
#pragma unroll
    for (int e = 0; e < NE; e++){
      unsigned long long m = __ballot(id == e);
      if (id == e){
        int pos = run[e] + __popcll(m & ltm);
        row_tok[pos] = tok;
        row_w[pos]   = wv[i];
      }
      run[e] += __popcll(m);
    }
  }
}

// ================= FAST PATH: all-glds, depth-2 counted-vmcnt pipeline =================

// -------- gate+up: 128m x 64n dual tile, BK=64 --------
__global__ __launch_bounds__(256, 2)
void k_gateup_f(const __hip_bfloat16* __restrict__ Xb, const __hip_bfloat16* __restrict__ Wtg,
                const __hip_bfloat16* __restrict__ Wtu, const int* __restrict__ row_tok,
                const int* __restrict__ off, __hip_bfloat16* __restrict__ hbuf){
  __shared__ __align__(16) char sA[2][16384];   // [128 m][64 k] bf16, slot^=(m&7)
  __shared__ __align__(16) char sBg[2][8192];   // [64 n][64 k] bf16, slot^=(n&7)
  __shared__ __align__(16) char sBu[2][8192];
  __shared__ int s_tok[128];

  const int bid = blockIdx.x;           // 2048 = 8e x 8mt x 32nt
  const int e  = bid & 7;
  const int mt = (bid >> 3) & 7;
  const int nt = bid >> 6;
  const int o0 = off[e], cnt = off[e + 1] - o0;
  if (mt * 128 >= cnt) return;
  const int p0 = o0 + mt * 128;
  const int cntL = min(128, cnt - mt * 128);
  const int tid = threadIdx.x;
  const int wid = tid >> 6, lane = tid & 63;

  if (tid < 128) s_tok[tid] = row_tok[min(p0 + tid, TT*2 - 1)];
  __syncthreads();

  const int lr = lane >> 3, ls = lane & 7;
  const int sw = ((ls ^ lr) & 7) << 4;          // inverse swizzle on source, linear dest
  const char* asrc[4];
#pragma unroll
  for (int i = 0; i < 4; i++){
    int r = (wid * 4 + i) * 8 + lr;
    asrc[i] = (const char*)Xb + (size_t)s_tok[r] * 4096 + sw;
  }
  const char* gsrc[2]; const char* usrc[2];
#pragma unroll
  for (int i = 0; i < 2; i++){
    int n = (wid * 2 + i) * 8 + lr;
    size_t rowb = (size_t)(e * 2048 + nt * 64 + n) * 4096;
    gsrc[i] = (const char*)Wtg + rowb + sw;
    usrc[i] = (const char*)Wtu + rowb + sw;
  }
  const int wm = wid >> 1, wn = wid & 1;        // 2x2 waves, each 64m x 32n (dual)
  const int kg = lane >> 4, ln = lane & 15;
  int aoff[2][4], boff[2][2];
#pragma unroll
  for (int ks = 0; ks < 2; ks++){
    int qs = ks * 4 + kg;
#pragma unroll
    for (int f = 0; f < 4; f++){
      int m = wm * 64 + f * 16 + ln;
      aoff[ks][f] = m * 128 + (((qs ^ (m & 7)) & 7) << 4);
    }
#pragma unroll
    for (int f = 0; f < 2; f++){
      int n = wn * 32 + f * 16 + ln;
      boff[ks][f] = n * 128 + (((qs ^ (n & 7)) & 7) << 4);
    }
  }

  f4 accg[4][2], accu[4][2];
#pragma unroll
  for (int a = 0; a < 4; a++)
#pragma unroll
    for (int b = 0; b < 2; b++){ accg[a][b] = f4{0,0,0,0}; accu[a][b] = f4{0,0,0,0}; }

#define GUSTAGE(buf, kt) do{ const int _o = (kt) * 128;                          \
    _Pragma("unroll") for (int i = 0; i < 4; i++)                                \
      glds16(asrc[i] + _o, &sA[buf][(wid * 4 + i) * 1024]);                      \
    _Pragma("unroll") for (int i = 0; i < 2; i++)                                \
      glds16(gsrc[i] + _o, &sBg[buf][(wid * 2 + i) * 1024]);                     \
    _Pragma("unroll") for (int i = 0; i < 2; i++)                                \
      glds16(usrc[i] + _o, &sBu[buf][(wid * 2 + i) * 1024]); }while(0)

  GUSTAGE(0, 0);                                 // 8 loads in flight (tile 0)
  for (int kt = 0; kt < 32; ++kt){
    const int cur = kt & 1;
    if (kt + 1 < 32){
      GUSTAGE(cur ^ 1, kt + 1);                  // +8 (tile kt+1); buf safe: tail barrier of kt-1
      asm volatile("s_waitcnt vmcnt(8)" ::: "memory");   // tile kt landed; kt+1 stays in flight
    } else {
      asm volatile("s_waitcnt vmcnt(0)" ::: "memory");   // last tile: full drain
    }
    __builtin_amdgcn_s_barrier();
    __builtin_amdgcn_sched_barrier(0);
    const char* A = &sA[cur][0];
    const char* G = &sBg[cur][0];
    const char* U = &sBu[cur][0];
#pragma unroll
    for (int ks = 0; ks < 2; ks++){
      short8 af[4];
#pragma unroll
      for (int f = 0; f < 4; f++) af[f] = *(const short8*)(A + aoff[ks][f]);
#pragma unroll
      for (int fn = 0; fn < 2; fn++){
        short8 bg = *(const short8*)(G + boff[ks][fn]);
        short8 bu = *(const short8*)(U + boff[ks][fn]);
#pragma unroll
        for (int fm = 0; fm < 4; fm++){
          accg[fm][fn] = __builtin_amdgcn_mfma_f32_16x16x32_bf16(af[fm], bg, accg[fm][fn], 0, 0, 0);
          accu[fm][fn] = __builtin_amdgcn_mfma_f32_16x16x32_bf16(af[fm], bu, accu[fm][fn], 0, 0, 0);
        }
      }
    }
    __builtin_amdgcn_sched_barrier(0);
    asm volatile("s_waitcnt lgkmcnt(0)" ::: "memory");
    __builtin_amdgcn_s_barrier();                // all waves done reading buf[cur]
    __builtin_amdgcn_sched_barrier(0);
  }
#undef GUSTAGE
  // epilogue: h = gelu(g)*u -> bf16
#pragma unroll
  for (int fm = 0; fm < 4; fm++){
#pragma unroll
    for (int r = 0; r < 4; r++){
      int row = wm * 64 + fm * 16 + (lane >> 4) * 4 + r;
      if (row < cntL){
        size_t base = (size_t)(p0 + row) * ID + (size_t)nt * 64 + wn * 32 + ln;
#pragma unroll
        for (int fn = 0; fn < 2; fn++){
          float g = accg[fm][fn][r];
          float u = accu[fm][fn][r];
          hbuf[base + fn * 16] = __float2bfloat16(gelu_t(g) * u);
        }
      }
    }
  }
}

// -------- down: 128m x 128n, BK=64 + weighted atomic scatter --------
__global__ __launch_bounds__(256, 2)
void k_down_f(const __hip_bfloat16* __restrict__ hbuf, const __hip_bfloat16* __restrict__ Wtd,
              const int* __restrict__ row_tok, const float* __restrict__ row_w,
              const int* __restrict__ off, float* __restrict__ out){
  __shared__ __align__(16) char sA[2][16384];   // [128 m][64 k]
  __shared__ __align__(16) char sB[2][16384];   // [128 n][64 k]
  __shared__ int s_tok[128];
  __shared__ float s_w[128];

  const int bid = blockIdx.x;           // 1024 = 8e x 8mt x 16nt
  const int e  = bid & 7;
  const int mt = (bid >> 3) & 7;
  const int nt = bid >> 6;
  const int o0 = off[e], cnt = off[e + 1] - o0;
  if (mt * 128 >= cnt) return;
  const int p0 = o0 + mt * 128;
  const int cntL = min(128, cnt - mt * 128);
  const int tid = threadIdx.x;
  const int wid = tid >> 6, lane = tid & 63;

  if (tid < 128){
    int p = min(p0 + tid, TT*2 - 1);
    s_tok[tid] = row_tok[p];
    s_w[tid]   = row_w[p];
  }
  __syncthreads();

  const int lr = lane >> 3, ls = lane & 7;
  const int sw = ((ls ^ lr) & 7) << 4;
  const char* asrc[4]; const char* bsrc[4];
#pragma unroll
  for (int i = 0; i < 4; i++){
    int r = (wid * 4 + i) * 8 + lr;
    int p = min(p0 + r, TT*2 - 1);
    asrc[i] = (const char*)hbuf + (size_t)p * 4096 + sw;
    bsrc[i] = (const char*)Wtd + (size_t)(e * 2048 + nt * 128 + r) * 4096 + sw;
  }
  const int wm = wid >> 1, wn = wid & 1;        // 2x2 waves: 64 x 64
  const int kg = lane >> 4, ln = lane & 15;
  int aoff[2][4], boff[2][4];
#pragma unroll
  for (int ks = 0; ks < 2; ks++){
    int qs = ks * 4 + kg;
#pragma unroll
    for (int f = 0; f < 4; f++){
      int m = wm * 64 + f * 16 + ln;
      aoff[ks][f] = m * 128 + (((qs ^ (m & 7)) & 7) << 4);
      int n = wn * 64 + f * 16 + ln;
      boff[ks][f] = n * 128 + (((qs ^ (n & 7)) & 7) << 4);
    }
  }

  f4 acc[4][4];
#pragma unroll
  for (int a = 0; a < 4; a++)
#pragma unroll
    for (int b = 0; b < 4; b++) acc[a][b] = f4{0,0,0,0};

#define DSTAGE(buf, kt) do{ const int _o = (kt) * 128;                           \
    _Pragma("unroll") for (int i = 0; i < 4; i++)                                \
      glds16(asrc[i] + _o, &sA[buf][(wid * 4 + i) * 1024]);                      \
    _Pragma("unroll") for (int i = 0; i < 4; i++)                                \
      glds16(bsrc[i] + _o, &sB[buf][(wid * 4 + i) * 1024]); }while(0)

  DSTAGE(0, 0);
  for (int kt = 0; kt < 32; ++kt){
    const int cur = kt & 1;
    if (kt + 1 < 32){
      DSTAGE(cur ^ 1, kt + 1);
      asm volatile("s_waitcnt vmcnt(8)" ::: "memory");
    } else {
      asm volatile("s_waitcnt vmcnt(0)" ::: "memory");
    }
    __builtin_amdgcn_s_barrier();
    __builtin_amdgcn_sched_barrier(0);
    const char* A = &sA[cur][0];
    const char* B = &sB[cur][0];
#pragma unroll
    for (int ks = 0; ks < 2; ks++){
      short8 af[4];
#pragma unroll
      for (int f = 0; f < 4; f++) af[f] = *(const short8*)(A + aoff[ks][f]);
#pragma unroll
      for (int fn = 0; fn < 4; fn++){
        short8 bf = *(const short8*)(B + boff[ks][fn]);
#pragma unroll
        for (int fm = 0; fm < 4; fm++)
          acc[fm][fn] = __builtin_amdgcn_mfma_f32_16x16x32_bf16(af[fm], bf, acc[fm][fn], 0, 0, 0);
      }
    }
    __builtin_amdgcn_sched_barrier(0);
    asm volatile("s_waitcnt lgkmcnt(0)" ::: "memory");
    __builtin_amdgcn_s_barrier();
    __builtin_amdgcn_sched_barrier(0);
  }
#undef DSTAGE
#pragma unroll
  for (int fm = 0; fm < 4; fm++){
#pragma unroll
    for (int r = 0; r < 4; r++){
      int row = wm * 64 + fm * 16 + (lane >> 4) * 4 + r;
      if (row < cntL){
        int tok = s_tok[row];
        float w = s_w[row];
        float* ob = out + (size_t)tok * HD + (size_t)nt * 128 + wn * 64 + ln;
#pragma unroll
        for (int fn = 0; fn < 4; fn++)
          atomicAdd(ob + fn * 16, acc[fm][fn][r] * w);
      }
    }
  }
}

// ================= FALLBACK PATH (round-3 kernels, known-good) =================

__global__ __launch_bounds__(256, 3)
void k_gateup_r3(const __hip_bfloat16* __restrict__ Xb, const float* __restrict__ Wg,
                 const float* __restrict__ Wu, const int* __restrict__ row_tok,
                 const int* __restrict__ off, __hip_bfloat16* __restrict__ hbuf){
  __shared__ __align__(16) char sA[2][16384];
  __shared__ __align__(16) char sBg[8192];
  __shared__ __align__(16) char sBu[8192];
  __shared__ int s_tok[128];

  const int bid = blockIdx.x;
  const int e  = bid & 7;
  const int mt = (bid >> 3) & 7;
  const int nt = bid >> 6;
  const int o0 = off[e], cnt = off[e + 1] - o0;
  if (mt * 128 >= cnt) return;
  const int p0 = o0 + mt * 128;
  const int cntL = min(128, cnt - mt * 128);
  const int tid = threadIdx.x;
  const int wid = tid >> 6, lane = tid & 63;

  if (tid < 128) s_tok[tid] = row_tok[min(p0 + tid, TT*2 - 1)];
  __syncthreads();

  const char* asrc[4];
#pragma unroll
  for (int i = 0; i < 4; i++){
    int c = wid * 4 + i;
    int r = c * 8 + (lane >> 3);
    asrc[i] = (const char*)Xb + (size_t)s_tok[r] * (HD * 2)
            + ((((lane & 7) ^ (lane >> 3)) & 7) << 4);
  }
  const int n0 = (tid & 15) * 4;
  const int k0 = (tid >> 4) * 4;
  const size_t wb = (size_t)e * HD * ID + (size_t)k0 * ID + (size_t)nt * 64 + n0;
  const float* gsrc = Wg + wb;
  const float* usrc = Wu + wb;
  int bw[4];
#pragma unroll
  for (int j = 0; j < 4; j++)
    bw[j] = (n0 + j) * 128 + ((((k0 >> 3) ^ (tid & 7) ^ (j << 1)) & 7) << 4) + ((k0 & 4) << 1);

  const int wm = wid >> 1, wn = wid & 1;
  const int kg = lane >> 4, ln = lane & 15;
  int aoff[2][4], boff[2][2];
#pragma unroll
  for (int ks = 0; ks < 2; ks++){
    int qs = ks * 4 + kg;
#pragma unroll
    for (int f = 0; f < 4; f++){
      int m = wm * 64 + f * 16 + ln;
      aoff[ks][f] = m * 128 + (((qs ^ (ln & 7)) & 7) << 4);
    }
#pragma unroll
    for (int f = 0; f < 2; f++){
      int n = wn * 32 + f * 16 + ln;
      boff[ks][f] = n * 128 + (((qs ^ swzB(n)) & 7) << 4);
    }
  }

  f4 accg[4][2], accu[4][2];
#pragma unroll
  for (int a = 0; a < 4; a++)
#pragma unroll
    for (int b = 0; b < 2; b++){ accg[a][b] = f4{0,0,0,0}; accu[a][b] = f4{0,0,0,0}; }

#pragma unroll
  for (int i = 0; i < 4; i++) glds16(asrc[i], &sA[0][(wid * 4 + i) * 1024]);
  f4 g0, g1, g2, g3, u0, u1, u2, u3;
  { const f4* p = (const f4*)gsrc; g0 = p[0]; g1 = p[ID/4]; g2 = p[ID/2]; g3 = p[3*ID/4];
    const f4* q = (const f4*)usrc; u0 = q[0]; u1 = q[ID/4]; u2 = q[ID/2]; u3 = q[3*ID/4]; }

  for (int kt = 0; kt < 32; ++kt){
    softbar();
    if (kt + 1 < 32){
      char* dst = &sA[(kt + 1) & 1][0] + (wid * 4) * 1024;
#pragma unroll
      for (int i = 0; i < 4; i++) glds16(asrc[i] + (size_t)(kt + 1) * 128, dst + i * 1024);
    }
#pragma unroll
    for (int j = 0; j < 4; j++){
      *(uint2*)(sBg + bw[j]) = uint2{ pk2(g0[j], g1[j]), pk2(g2[j], g3[j]) };
      *(uint2*)(sBu + bw[j]) = uint2{ pk2(u0[j], u1[j]), pk2(u2[j], u3[j]) };
    }
    softbar();
    if (kt + 1 < 32){
      const f4* p = (const f4*)(gsrc + (size_t)(kt + 1) * 64 * ID);
      g0 = p[0]; g1 = p[ID/4]; g2 = p[ID/2]; g3 = p[3*ID/4];
      const f4* q = (const f4*)(usrc + (size_t)(kt + 1) * 64 * ID);
      u0 = q[0]; u1 = q[ID/4]; u2 = q[ID/2]; u3 = q[3*ID/4];
    }
    const char* A = &sA[kt & 1][0];
#pragma unroll
    for (int ks = 0; ks < 2; ks++){
      short8 af[4];
#pragma unroll
      for (int f = 0; f < 4; f++) af[f] = *(const short8*)(A + aoff[ks][f]);
#pragma unroll
      for (int fn = 0; fn < 2; fn++){
        short8 bg = *(const short8*)(sBg + boff[ks][fn]);
        short8 bu = *(const short8*)(sBu + boff[ks][fn]);
#pragma unroll
        for (int fm = 0; fm < 4; fm++){
          accg[fm][fn] = __builtin_amdgcn_mfma_f32_16x16x32_bf16(af[fm], bg, accg[fm][fn], 0, 0, 0);
          accu[fm][fn] = __builtin_amdgcn_mfma_f32_16x16x32_bf16(af[fm], bu, accu[fm][fn], 0, 0, 0);
        }
      }
    }
  }
#pragma unroll
  for (int fm = 0; fm < 4; fm++){
#pragma unroll
    for (int r = 0; r < 4; r++){
      int row = wm * 64 + fm * 16 + (lane >> 4) * 4 + r;
      if (row < cntL){
        size_t base = (size_t)(p0 + row) * ID + (size_t)nt * 64 + wn * 32 + ln;
#pragma unroll
        for (int fn = 0; fn < 2; fn++){
          float g = accg[fm][fn][r];
          float u = accu[fm][fn][r];
          hbuf[base + fn * 16] = __float2bfloat16(gelu_t(g) * u);
        }
      }
    }
  }
}

__global__ __launch_bounds__(256, 3)
void k_down_r3(const __hip_bfloat16* __restrict__ hbuf, const float* __restrict__ Wd,
               const int* __restrict__ row_tok, const float* __restrict__ row_w,
               const int* __restrict__ off, float* __restrict__ out){
  __shared__ __align__(16) char sA[2][16384];
  __shared__ __align__(16) char sB[16384];
  __shared__ int s_tok[128];
  __shared__ float s_w[128];

  const int bid = blockIdx.x;
  const int e  = bid & 7;
  const int mt = (bid >> 3) & 7;
  const int nt = bid >> 6;
  const int o0 = off[e], cnt = off[e + 1] - o0;
  if (mt * 128 >= cnt) return;
  const int p0 = o0 + mt * 128;
  const int cntL = min(128, cnt - mt * 128);
  const int tid = threadIdx.x;
  const int wid = tid >> 6, lane = tid & 63;

  if (tid < 128){
    int p = min(p0 + tid, TT*2 - 1);
    s_tok[tid] = row_tok[p];
    s_w[tid]   = row_w[p];
  }
  __syncthreads();

  const char* asrc[4];
#pragma unroll
  for (int i = 0; i < 4; i++){
    int c = wid * 4 + i;
    int r = c * 8 + (lane >> 3);
    int p = min(p0 + r, TT*2 - 1);
    asrc[i] = (const char*)hbuf + (size_t)p * (ID * 2)
            + ((((lane & 7) ^ (lane >> 3)) & 7) << 4);
  }
  const int n0 = (tid & 31) * 4;
  const int k0 = (tid >> 5) * 8;
  const float* bsrc = Wd + (size_t)e * ID * HD + (size_t)k0 * HD + (size_t)nt * 128 + n0;
  int bw[4];
#pragma unroll
  for (int j = 0; j < 4; j++)
    bw[j] = (n0 + j) * 128 + ((((k0 >> 3) ^ (tid & 7) ^ (j << 1)) & 7) << 4);

  const int wm = wid >> 1, wn = wid & 1;
  const int kg = lane >> 4, ln = lane & 15;
  int aoff[2][4], boff[2][4];
#pragma unroll
  for (int ks = 0; ks < 2; ks++){
    int qs = ks * 4 + kg;
#pragma unroll
    for (int f = 0; f < 4; f++){
      int m = wm * 64 + f * 16 + ln;
      aoff[ks][f] = m * 128 + (((qs ^ (ln & 7)) & 7) << 4);
      int n = wn * 64 + f * 16 + ln;
      boff[ks][f] = n * 128 + (((qs ^ swzB(n)) & 7) << 4);
    }
  }

  f4 acc[4][4];
#pragma unroll
  for (int a = 0; a < 4; a++)
#pragma unroll
    for (int b = 0; b < 4; b++) acc[a][b] = f4{0,0,0,0};

#pragma unroll
  for (int i = 0; i < 4; i++) glds16(asrc[i], &sA[0][(wid * 4 + i) * 1024]);
  f4 r0, r1, r2, r3, r4, r5, r6, r7;
  { const f4* p = (const f4*)bsrc;
    r0 = p[0]; r1 = p[HD/4]; r2 = p[HD/2]; r3 = p[3*HD/4];
    r4 = p[HD]; r5 = p[5*HD/4]; r6 = p[3*HD/2]; r7 = p[7*HD/4]; }

  for (int kt = 0; kt < 32; ++kt){
    softbar();
    if (kt + 1 < 32){
      char* dst = &sA[(kt + 1) & 1][0] + (wid * 4) * 1024;
#pragma unroll
      for (int i = 0; i < 4; i++) glds16(asrc[i] + (size_t)(kt + 1) * 128, dst + i * 1024);
    }
#pragma unroll
    for (int j = 0; j < 4; j++){
      *(uint4*)(sB + bw[j]) = uint4{ pk2(r0[j], r1[j]), pk2(r2[j], r3[j]),
                                     pk2(r4[j], r5[j]), pk2(r6[j], r7[j]) };
    }
    softbar();
    if (kt + 1 < 32){
      const f4* p = (const f4*)(bsrc + (size_t)(kt + 1) * 64 * HD);
      r0 = p[0]; r1 = p[HD/4]; r2 = p[HD/2]; r3 = p[3*HD/4];
      r4 = p[HD]; r5 = p[5*HD/4]; r6 = p[3*HD/2]; r7 = p[7*HD/4];
    }
    const char* A = &sA[kt & 1][0];
#pragma unroll
    for (int ks = 0; ks < 2; ks++){
      short8 af[4];
#pragma unroll
      for (int f = 0; f < 4; f++) af[f] = *(const short8*)(A + aoff[ks][f]);
#pragma unroll
      for (int fn = 0; fn < 4; fn++){
        short8 bf = *(const short8*)(sB + boff[ks][fn]);
#pragma unroll
        for (int fm = 0; fm < 4; fm++)
          acc[fm][fn] = __builtin_amdgcn_mfma_f32_16x16x32_bf16(af[fm], bf, acc[fm][fn], 0, 0, 0);
      }
    }
  }
#pragma unroll
  for (int fm = 0; fm < 4; fm++){
#pragma unroll
    for (int r = 0; r < 4; r++){
      int row = wm * 64 + fm * 16 + (lane >> 4) * 4 + r;
      if (row < cntL){
        int tok = s_tok[row];
        float w = s_w[row];
        float* ob = out + (size_t)tok * HD + (size_t)nt * 128 + wn * 64 + ln;
#pragma unroll
        for (int fn = 0; fn < 4; fn++)
          atomicAdd(ob + fn * 16, acc[fm][fn][r] * w);
      }
    }
  }
}

extern "C" void kernel_launch(void* const* d_in, const int* in_sizes, int n_in,
                              void* d_out, int out_size, void* d_ws, size_t ws_size,
                              hipStream_t stream){
  (void)in_sizes; (void)n_in; (void)out_size;
  const float* X  = (const float*)d_in[0];
  const float* RL = (const float*)d_in[1];
  const float* SC = (const float*)d_in[2];
  const float* Wg = (const float*)d_in[3];
  const float* Wu = (const float*)d_in[4];
  const float* Wd = (const float*)d_in[5];
  float* out = (float*)d_out;

  char* ws = (char*)d_ws;
  int*   rid     = (int*)(ws);
  float* rw      = (float*)(ws + 16384);
  int*   row_tok = (int*)(ws + 32768);
  float* row_w   = (float*)(ws + 49152);
  int*   off     = (int*)(ws + 65536);
  __hip_bfloat16* hbuf = (__hip_bfloat16*)(ws + 66560);                      // 16 MiB
  __hip_bfloat16* Xb   = (__hip_bfloat16*)(ws + 66560 + 16777216ull);        // 8 MiB
  __hip_bfloat16* Wb   = (__hip_bfloat16*)(ws + 66560 + 16777216ull + 8388608ull);
  const size_t WME = (size_t)NE * 2048 * 2048;                               // elems per tensor
  const size_t need = 66560ull + 16777216ull + 8388608ull + 3ull * WME * 2ull;

  hipMemsetAsync(d_out, 0, (size_t)TT * HD * sizeof(float), stream);
  k_cvtx <<<2048, 256, 0, stream>>>(X, Xb);
  k_route<<<TT / 256, 256, 0, stream>>>(RL, SC, rid, rw);
  k_lists<<<1, 64, 0, stream>>>(rid, rw, row_tok, row_w, off);

  if (ws_size >= need){
    k_cvtw<<<12288, 256, 0, stream>>>(Wg, Wu, Wd, Wb);
    k_gateup_f<<<2048, 256, 0, stream>>>(Xb, Wb, Wb + WME, row_tok, off, hbuf);
    k_down_f  <<<1024, 256, 0, stream>>>(hbuf, Wb + 2 * WME, row_tok, row_w, off, out);
  } else {
    k_gateup_r3<<<2048, 256, 0, stream>>>(Xb, Wg, Wu, row_tok, off, hbuf);
    k_down_r3  <<<1024, 256, 0, stream>>>(hbuf, Wd, row_tok, row_w, off, out);
  }
}

// Round 7
// 441.190 us; speedup vs baseline: 2.1762x; 1.0510x over previous
//
#include <hip/hip_runtime.h>
#include <hip/hip_bf16.h>

#define TT 2048
#define HD 2048
#define ID 2048
#define NE 8

typedef __attribute__((ext_vector_type(8))) short short8;
typedef __attribute__((ext_vector_type(4))) float f4;

__device__ __forceinline__ unsigned short b16(float f){
  union { __hip_bfloat16 b; unsigned short u; } x;
  x.b = __float2bfloat16(f);
  return x.u;
}
__device__ __forceinline__ unsigned pk2(float lo, float hi){
  return (unsigned)b16(lo) | ((unsigned)b16(hi) << 16);
}
__device__ __forceinline__ float gelu_t(float x){
  float y = 0.7978845608028654f * (x + 0.044715f * x * x * x);
  float t = 1.0f - 2.0f / (__expf(2.0f * y) + 1.0f);
  return 0.5f * x * (1.0f + t);
}
__device__ __forceinline__ void glds16(const void* g, void* l){
  __builtin_amdgcn_global_load_lds(
      (const __attribute__((address_space(1))) unsigned*)g,
      (__attribute__((address_space(3))) unsigned*)l, 16, 0, 0);
}
__device__ __forceinline__ void softbar(){
  asm volatile("s_waitcnt lgkmcnt(0)" ::: "memory");
  __builtin_amdgcn_s_barrier();
  __builtin_amdgcn_sched_barrier(0);
}
__device__ __forceinline__ int swzB(int n){ return (((n >> 2) & 7) ^ ((n & 3) << 1)) & 7; }

// ---------------- X fp32 -> bf16 ----------------
__global__ void k_cvtx(const float* __restrict__ X, __hip_bfloat16* __restrict__ Xb){
  int i = blockIdx.x * 256 + threadIdx.x;
  const f4* src = (const f4*)X + (size_t)i * 2;
  f4 a = src[0], b = src[1];
  uint4 o = { pk2(a[0],a[1]), pk2(a[2],a[3]), pk2(b[0],b[1]), pk2(b[2],b[3]) };
  ((uint4*)Xb)[i] = o;
}

// -------- W fp32 [e][k][n] -> bf16 [e][n][k] (transpose-convert), tile 128k x 64n --------
__global__ __launch_bounds__(256)
void k_cvtw(const float* __restrict__ Wg, const float* __restrict__ Wu,
            const float* __restrict__ Wd, __hip_bfloat16* __restrict__ Wb){
  __shared__ float s_t[128 * 65];
  const int bid = blockIdx.x;                 // 3 x 8 x 16kt x 32nt = 12288
  const int nt = bid & 31;
  const int kt = (bid >> 5) & 15;
  const int e  = (bid >> 9) & 7;
  const int m  = bid >> 12;
  const float* S = (m == 0 ? Wg : (m == 1 ? Wu : Wd))
                 + (size_t)e * HD * ID + (size_t)(kt * 128) * 2048 + nt * 64;
  __hip_bfloat16* D = Wb + (size_t)m * ((size_t)NE * 2048 * 2048)
                    + (size_t)(e * 2048 + nt * 64) * 2048 + kt * 128;
  const int tid = threadIdx.x;
  const int col4 = tid & 15, rq = tid >> 4;
#pragma unroll
  for (int i = 0; i < 8; i++){
    int row = i * 16 + rq;
    f4 v = *(const f4*)(S + (size_t)row * 2048 + col4 * 4);
#pragma unroll
    for (int j = 0; j < 4; j++) s_t[row * 65 + col4 * 4 + j] = v[j];
  }
  __syncthreads();
  const int n2 = tid >> 2, kc = (tid & 3) * 32;
  unsigned o[16];
#pragma unroll
  for (int a = 0; a < 16; a++){
    float lo = s_t[(kc + a * 2) * 65 + n2];
    float hi = s_t[(kc + a * 2 + 1) * 65 + n2];
    o[a] = pk2(lo, hi);
  }
  char* dp = (char*)(D + (size_t)n2 * 2048 + kc);
#pragma unroll
  for (int a = 0; a < 4; a++)
    *(uint4*)(dp + a * 16) = uint4{ o[a*4], o[a*4+1], o[a*4+2], o[a*4+3] };
}

// ---------------- routing ----------------
__global__ void k_route(const float* __restrict__ lg, const float* __restrict__ sc,
                        int* __restrict__ rid, float* __restrict__ rw){
  int t = blockIdx.x * blockDim.x + threadIdx.x;
  if (t >= TT) return;
  float l[NE];
#pragma unroll
  for (int e = 0; e < NE; e++) l[e] = lg[t * NE + e];
  float mx = l[0];
#pragma unroll
  for (int e = 1; e < NE; e++) mx = fmaxf(mx, l[e]);
  float p[NE];
#pragma unroll
  for (int e = 0; e < NE; e++) p[e] = __expf(l[e] - mx);
  int i0 = 0; float b0 = l[0];
#pragma unroll
  for (int e = 1; e < NE; e++) if (l[e] > b0){ b0 = l[e]; i0 = e; }
  int i1 = -1; float b1 = -1e30f;
#pragma unroll
  for (int e = 0; e < NE; e++) if (e != i0 && l[e] > b1){ b1 = l[e]; i1 = e; }
  float p0 = p[i0], p1 = p[i1];
  float rn = p0 + p1; rn = (rn > 0.f) ? rn : 1.f;
  rw[t*2]   = p0 / rn * sc[i0];
  rw[t*2+1] = p1 / rn * sc[i1];
  rid[t*2]  = i0;
  rid[t*2+1]= i1;
}

// ---------------- deterministic per-expert compaction ----------------
__global__ void k_lists(const int* __restrict__ rid, const float* __restrict__ rw,
                        int* __restrict__ row_tok, float* __restrict__ row_w,
                        int* __restrict__ off){
  int lane = threadIdx.x;            // 64 threads
  int ids[64]; float wv[64];
#pragma unroll
  for (int i = 0; i < 64; i++) ids[i] = rid[i * 64 + lane];
#pragma unroll
  for (int i = 0; i < 64; i++) wv[i] = rw[i * 64 + lane];
  int cnt[NE];
#pragma unroll
  for (int e = 0; e < NE; e++) cnt[e] = 0;
#pragma unroll
  for (int i = 0; i < 64; i++){
#pragma unroll
    for (int e = 0; e < NE; e++)
      cnt[e] += __popcll(__ballot(ids[i] == e));
  }
  int offs[NE + 1]; offs[0] = 0;
#pragma unroll
  for (int e = 0; e < NE; e++) offs[e + 1] = offs[e] + cnt[e];
  if (lane == 0){
#pragma unroll
    for (int e = 0; e <= NE; e++) off[e] = offs[e];
  }
  int run[NE];
#pragma unroll
  for (int e = 0; e < NE; e++) run[e] = offs[e];
  unsigned long long ltm = (1ULL << lane) - 1ULL;
#pragma unroll
  for (int i = 0; i < 64; i++){
    int id = ids[i];
    int tok = (i * 64 + lane) >> 1;
#pragma unroll
    for (int e = 0; e < NE; e++){
      unsigned long long m = __ballot(id == e);
      if (id == e){
        int pos = run[e] + __popcll(m & ltm);
        row_tok[pos] = tok;
        row_w[pos]   = wv[i];
      }
      run[e] += __popcll(m);
    }
  }
}

// ================= FAST PATH: BK=32, wave 64x64, glds-only, counted vmcnt =================
// LDS row = 64B (4 slots of 16B); swizzle slot' = slot ^ ((row>>1)&3)  -> 2-way (free) reads.

// -------- gate+up: block 128m x 128n DUAL, wave 64x64 dual (fm=4,fn=4,nmat=2, r=2.67) --------
__global__ __launch_bounds__(256, 2)
void k_gateup_f(const __hip_bfloat16* __restrict__ Xb, const __hip_bfloat16* __restrict__ Wtg,
                const __hip_bfloat16* __restrict__ Wtu, const int* __restrict__ row_tok,
                const int* __restrict__ off, __hip_bfloat16* __restrict__ hbuf){
  __shared__ __align__(16) char sA[2][8192];    // [128 m][32 k] bf16
  __shared__ __align__(16) char sBg[2][8192];   // [128 n][32 k] bf16
  __shared__ __align__(16) char sBu[2][8192];
  __shared__ int s_tok[128];

  const int bid = blockIdx.x;           // 1024 = 8e x 8mt x 16nt (e == XCD pin)
  const int e  = bid & 7;
  const int mt = (bid >> 3) & 7;
  const int nt = bid >> 6;              // 0..15
  const int o0 = off[e], cnt = off[e + 1] - o0;
  if (mt * 128 >= cnt) return;
  const int p0 = o0 + mt * 128;
  const int cntL = min(128, cnt - mt * 128);
  const int tid = threadIdx.x;
  const int wid = tid >> 6, lane = tid & 63;

  if (tid < 128) s_tok[tid] = row_tok[min(p0 + tid, TT*2 - 1)];
  __syncthreads();

  // staging: chunk = 1KB = 16 rows x 64B; lane l -> row l>>2, slot l&3
  // inverse swizzle on source: slot' = (l&3) ^ ((l>>3)&3)
  const int sw = (((lane & 3) ^ ((lane >> 3) & 3)) << 4);
  const char* asrc[2]; const char* gsrc[2]; const char* usrc[2];
#pragma unroll
  for (int i = 0; i < 2; i++){
    int r = (wid * 2 + i) * 16 + (lane >> 2);
    asrc[i] = (const char*)Xb + (size_t)s_tok[r] * 4096 + sw;
    size_t rowb = (size_t)(e * 2048 + nt * 128 + r) * 4096;
    gsrc[i] = (const char*)Wtg + rowb + sw;
    usrc[i] = (const char*)Wtu + rowb + sw;
  }
  const int wm = wid >> 1, wn = wid & 1;        // 2x2 waves, wave = 64m x 64n (dual)
  const int kg = lane >> 4, ln = lane & 15;
  int aoff[4], boff[4];
#pragma unroll
  for (int f = 0; f < 4; f++){
    int m = wm * 64 + f * 16 + ln;
    aoff[f] = m * 64 + (((kg ^ ((m >> 1) & 3)) & 3) << 4);
    int n = wn * 64 + f * 16 + ln;
    boff[f] = n * 64 + (((kg ^ ((n >> 1) & 3)) & 3) << 4);
  }

  f4 accg[4][4], accu[4][4];
#pragma unroll
  for (int a = 0; a < 4; a++)
#pragma unroll
    for (int b = 0; b < 4; b++){ accg[a][b] = f4{0,0,0,0}; accu[a][b] = f4{0,0,0,0}; }

#define GUSTAGE(buf, kt) do{ const int _o = (kt) * 64;                           \
    _Pragma("unroll") for (int i = 0; i < 2; i++)                                \
      glds16(asrc[i] + _o, &sA[buf][(wid * 2 + i) * 1024]);                      \
    _Pragma("unroll") for (int i = 0; i < 2; i++)                                \
      glds16(gsrc[i] + _o, &sBg[buf][(wid * 2 + i) * 1024]);                     \
    _Pragma("unroll") for (int i = 0; i < 2; i++)                                \
      glds16(usrc[i] + _o, &sBu[buf][(wid * 2 + i) * 1024]); }while(0)

  GUSTAGE(0, 0);
  for (int kt = 0; kt < 64; ++kt){
    const int cur = kt & 1;
    if (kt + 1 < 64){
      GUSTAGE(cur ^ 1, kt + 1);                  // buf safe: previous bottom barrier
      asm volatile("s_waitcnt vmcnt(6)" ::: "memory");   // tile kt landed; kt+1 in flight
    } else {
      asm volatile("s_waitcnt vmcnt(0)" ::: "memory");
    }
    __builtin_amdgcn_s_barrier();
    __builtin_amdgcn_sched_barrier(0);
    const char* A = &sA[cur][0];
    const char* G = &sBg[cur][0];
    const char* U = &sBu[cur][0];
    short8 af[4];
#pragma unroll
    for (int f = 0; f < 4; f++) af[f] = *(const short8*)(A + aoff[f]);
#pragma unroll
    for (int fn = 0; fn < 4; fn++){
      short8 bg = *(const short8*)(G + boff[fn]);
      short8 bu = *(const short8*)(U + boff[fn]);
#pragma unroll
      for (int fm = 0; fm < 4; fm++){
        accg[fm][fn] = __builtin_amdgcn_mfma_f32_16x16x32_bf16(af[fm], bg, accg[fm][fn], 0, 0, 0);
        accu[fm][fn] = __builtin_amdgcn_mfma_f32_16x16x32_bf16(af[fm], bu, accu[fm][fn], 0, 0, 0);
      }
    }
    __builtin_amdgcn_sched_barrier(0);
    asm volatile("s_waitcnt lgkmcnt(0)" ::: "memory");
    __builtin_amdgcn_s_barrier();
    __builtin_amdgcn_sched_barrier(0);
  }
#undef GUSTAGE
  // epilogue: h = gelu(g)*u -> bf16
#pragma unroll
  for (int fm = 0; fm < 4; fm++){
#pragma unroll
    for (int r = 0; r < 4; r++){
      int row = wm * 64 + fm * 16 + (lane >> 4) * 4 + r;
      if (row < cntL){
        size_t base = (size_t)(p0 + row) * ID + (size_t)nt * 128 + wn * 64 + ln;
#pragma unroll
        for (int fn = 0; fn < 4; fn++){
          float g = accg[fm][fn][r];
          float u = accu[fm][fn][r];
          hbuf[base + fn * 16] = __float2bfloat16(gelu_t(g) * u);
        }
      }
    }
  }
}

// -------- down: block 128m x 128n, wave 64x64, BK=32, 3 blocks/CU + atomic scatter --------
__global__ __launch_bounds__(256, 3)
void k_down_f(const __hip_bfloat16* __restrict__ hbuf, const __hip_bfloat16* __restrict__ Wtd,
              const int* __restrict__ row_tok, const float* __restrict__ row_w,
              const int* __restrict__ off, float* __restrict__ out){
  __shared__ __align__(16) char sA[2][8192];    // [128 m][32 k]
  __shared__ __align__(16) char sB[2][8192];    // [128 n][32 k]
  __shared__ int s_tok[128];
  __shared__ float s_w[128];

  const int bid = blockIdx.x;           // 1024 = 8e x 8mt x 16nt
  const int e  = bid & 7;
  const int mt = (bid >> 3) & 7;
  const int nt = bid >> 6;
  const int o0 = off[e], cnt = off[e + 1] - o0;
  if (mt * 128 >= cnt) return;
  const int p0 = o0 + mt * 128;
  const int cntL = min(128, cnt - mt * 128);
  const int tid = threadIdx.x;
  const int wid = tid >> 6, lane = tid & 63;

  if (tid < 128){
    int p = min(p0 + tid, TT*2 - 1);
    s_tok[tid] = row_tok[p];
    s_w[tid]   = row_w[p];
  }
  __syncthreads();

  const int sw = (((lane & 3) ^ ((lane >> 3) & 3)) << 4);
  const char* asrc[2]; const char* bsrc[2];
#pragma unroll
  for (int i = 0; i < 2; i++){
    int r = (wid * 2 + i) * 16 + (lane >> 2);
    int p = min(p0 + r, TT*2 - 1);
    asrc[i] = (const char*)hbuf + (size_t)p * 4096 + sw;
    bsrc[i] = (const char*)Wtd + (size_t)(e * 2048 + nt * 128 + r) * 4096 + sw;
  }
  const int wm = wid >> 1, wn = wid & 1;
  const int kg = lane >> 4, ln = lane & 15;
  int aoff[4], boff[4];
#pragma unroll
  for (int f = 0; f < 4; f++){
    int m = wm * 64 + f * 16 + ln;
    aoff[f] = m * 64 + (((kg ^ ((m >> 1) & 3)) & 3) << 4);
    int n = wn * 64 + f * 16 + ln;
    boff[f] = n * 64 + (((kg ^ ((n >> 1) & 3)) & 3) << 4);
  }

  f4 acc[4][4];
#pragma unroll
  for (int a = 0; a < 4; a++)
#pragma unroll
    for (int b = 0; b < 4; b++) acc[a][b] = f4{0,0,0,0};

#define DSTAGE(buf, kt) do{ const int _o = (kt) * 64;                            \
    _Pragma("unroll") for (int i = 0; i < 2; i++)                                \
      glds16(asrc[i] + _o, &sA[buf][(wid * 2 + i) * 1024]);                      \
    _Pragma("unroll") for (int i = 0; i < 2; i++)                                \
      glds16(bsrc[i] + _o, &sB[buf][(wid * 2 + i) * 1024]); }while(0)

  DSTAGE(0, 0);
  for (int kt = 0; kt < 64; ++kt){
    const int cur = kt & 1;
    if (kt + 1 < 64){
      DSTAGE(cur ^ 1, kt + 1);
      asm volatile("s_waitcnt vmcnt(4)" ::: "memory");
    } else {
      asm volatile("s_waitcnt vmcnt(0)" ::: "memory");
    }
    __builtin_amdgcn_s_barrier();
    __builtin_amdgcn_sched_barrier(0);
    const char* A = &sA[cur][0];
    const char* B = &sB[cur][0];
    short8 af[4];
#pragma unroll
    for (int f = 0; f < 4; f++) af[f] = *(const short8*)(A + aoff[f]);
#pragma unroll
    for (int fn = 0; fn < 4; fn++){
      short8 bf = *(const short8*)(B + boff[fn]);
#pragma unroll
      for (int fm = 0; fm < 4; fm++)
        acc[fm][fn] = __builtin_amdgcn_mfma_f32_16x16x32_bf16(af[fm], bf, acc[fm][fn], 0, 0, 0);
    }
    __builtin_amdgcn_sched_barrier(0);
    asm volatile("s_waitcnt lgkmcnt(0)" ::: "memory");
    __builtin_amdgcn_s_barrier();
    __builtin_amdgcn_sched_barrier(0);
  }
#undef DSTAGE
#pragma unroll
  for (int fm = 0; fm < 4; fm++){
#pragma unroll
    for (int r = 0; r < 4; r++){
      int row = wm * 64 + fm * 16 + (lane >> 4) * 4 + r;
      if (row < cntL){
        int tok = s_tok[row];
        float w = s_w[row];
        float* ob = out + (size_t)tok * HD + (size_t)nt * 128 + wn * 64 + ln;
#pragma unroll
        for (int fn = 0; fn < 4; fn++)
          atomicAdd(ob + fn * 16, acc[fm][fn][r] * w);
      }
    }
  }
}

// ================= FALLBACK PATH (round-3 kernels, known-good) =================

__global__ __launch_bounds__(256, 3)
void k_gateup_r3(const __hip_bfloat16* __restrict__ Xb, const float* __restrict__ Wg,
                 const float* __restrict__ Wu, const int* __restrict__ row_tok,
                 const int* __restrict__ off, __hip_bfloat16* __restrict__ hbuf){
  __shared__ __align__(16) char sA[2][16384];
  __shared__ __align__(16) char sBg[8192];
  __shared__ __align__(16) char sBu[8192];
  __shared__ int s_tok[128];

  const int bid = blockIdx.x;
  const int e  = bid & 7;
  const int mt = (bid >> 3) & 7;
  const int nt = bid >> 6;
  const int o0 = off[e], cnt = off[e + 1] - o0;
  if (mt * 128 >= cnt) return;
  const int p0 = o0 + mt * 128;
  const int cntL = min(128, cnt - mt * 128);
  const int tid = threadIdx.x;
  const int wid = tid >> 6, lane = tid & 63;

  if (tid < 128) s_tok[tid] = row_tok[min(p0 + tid, TT*2 - 1)];
  __syncthreads();

  const char* asrc[4];
#pragma unroll
  for (int i = 0; i < 4; i++){
    int c = wid * 4 + i;
    int r = c * 8 + (lane >> 3);
    asrc[i] = (const char*)Xb + (size_t)s_tok[r] * (HD * 2)
            + ((((lane & 7) ^ (lane >> 3)) & 7) << 4);
  }
  const int n0 = (tid & 15) * 4;
  const int k0 = (tid >> 4) * 4;
  const size_t wb = (size_t)e * HD * ID + (size_t)k0 * ID + (size_t)nt * 64 + n0;
  const float* gsrc = Wg + wb;
  const float* usrc = Wu + wb;
  int bw[4];
#pragma unroll
  for (int j = 0; j < 4; j++)
    bw[j] = (n0 + j) * 128 + ((((k0 >> 3) ^ (tid & 7) ^ (j << 1)) & 7) << 4) + ((k0 & 4) << 1);

  const int wm = wid >> 1, wn = wid & 1;
  const int kg = lane >> 4, ln = lane & 15;
  int aoff[2][4], boff[2][2];
#pragma unroll
  for (int ks = 0; ks < 2; ks++){
    int qs = ks * 4 + kg;
#pragma unroll
    for (int f = 0; f < 4; f++){
      int m = wm * 64 + f * 16 + ln;
      aoff[ks][f] = m * 128 + (((qs ^ (ln & 7)) & 7) << 4);
    }
#pragma unroll
    for (int f = 0; f < 2; f++){
      int n = wn * 32 + f * 16 + ln;
      boff[ks][f] = n * 128 + (((qs ^ swzB(n)) & 7) << 4);
    }
  }

  f4 accg[4][2], accu[4][2];
#pragma unroll
  for (int a = 0; a < 4; a++)
#pragma unroll
    for (int b = 0; b < 2; b++){ accg[a][b] = f4{0,0,0,0}; accu[a][b] = f4{0,0,0,0}; }

#pragma unroll
  for (int i = 0; i < 4; i++) glds16(asrc[i], &sA[0][(wid * 4 + i) * 1024]);
  f4 g0, g1, g2, g3, u0, u1, u2, u3;
  { const f4* p = (const f4*)gsrc; g0 = p[0]; g1 = p[ID/4]; g2 = p[ID/2]; g3 = p[3*ID/4];
    const f4* q = (const f4*)usrc; u0 = q[0]; u1 = q[ID/4]; u2 = q[ID/2]; u3 = q[3*ID/4]; }

  for (int kt = 0; kt < 32; ++kt){
    softbar();
    if (kt + 1 < 32){
      char* dst = &sA[(kt + 1) & 1][0] + (wid * 4) * 1024;
#pragma unroll
      for (int i = 0; i < 4; i++) glds16(asrc[i] + (size_t)(kt + 1) * 128, dst + i * 1024);
    }
#pragma unroll
    for (int j = 0; j < 4; j++){
      *(uint2*)(sBg + bw[j]) = uint2{ pk2(g0[j], g1[j]), pk2(g2[j], g3[j]) };
      *(uint2*)(sBu + bw[j]) = uint2{ pk2(u0[j], u1[j]), pk2(u2[j], u3[j]) };
    }
    softbar();
    if (kt + 1 < 32){
      const f4* p = (const f4*)(gsrc + (size_t)(kt + 1) * 64 * ID);
      g0 = p[0]; g1 = p[ID/4]; g2 = p[ID/2]; g3 = p[3*ID/4];
      const f4* q = (const f4*)(usrc + (size_t)(kt + 1) * 64 * ID);
      u0 = q[0]; u1 = q[ID/4]; u2 = q[ID/2]; u3 = q[3*ID/4];
    }
    const char* A = &sA[kt & 1][0];
#pragma unroll
    for (int ks = 0; ks < 2; ks++){
      short8 af[4];
#pragma unroll
      for (int f = 0; f < 4; f++) af[f] = *(const short8*)(A + aoff[ks][f]);
#pragma unroll
      for (int fn = 0; fn < 2; fn++){
        short8 bg = *(const short8*)(sBg + boff[ks][fn]);
        short8 bu = *(const short8*)(sBu + boff[ks][fn]);
#pragma unroll
        for (int fm = 0; fm < 4; fm++){
          accg[fm][fn] = __builtin_amdgcn_mfma_f32_16x16x32_bf16(af[fm], bg, accg[fm][fn], 0, 0, 0);
          accu[fm][fn] = __builtin_amdgcn_mfma_f32_16x16x32_bf16(af[fm], bu, accu[fm][fn], 0, 0, 0);
        }
      }
    }
  }
#pragma unroll
  for (int fm = 0; fm < 4; fm++){
#pragma unroll
    for (int r = 0; r < 4; r++){
      int row = wm * 64 + fm * 16 + (lane >> 4) * 4 + r;
      if (row < cntL){
        size_t base = (size_t)(p0 + row) * ID + (size_t)nt * 64 + wn * 32 + ln;
#pragma unroll
        for (int fn = 0; fn < 2; fn++){
          float g = accg[fm][fn][r];
          float u = accu[fm][fn][r];
          hbuf[base + fn * 16] = __float2bfloat16(gelu_t(g) * u);
        }
      }
    }
  }
}

__global__ __launch_bounds__(256, 3)
void k_down_r3(const __hip_bfloat16* __restrict__ hbuf, const float* __restrict__ Wd,
               const int* __restrict__ row_tok, const float* __restrict__ row_w,
               const int* __restrict__ off, float* __restrict__ out){
  __shared__ __align__(16) char sA[2][16384];
  __shared__ __align__(16) char sB[16384];
  __shared__ int s_tok[128];
  __shared__ float s_w[128];

  const int bid = blockIdx.x;
  const int e  = bid & 7;
  const int mt = (bid >> 3) & 7;
  const int nt = bid >> 6;
  const int o0 = off[e], cnt = off[e + 1] - o0;
  if (mt * 128 >= cnt) return;
  const int p0 = o0 + mt * 128;
  const int cntL = min(128, cnt - mt * 128);
  const int tid = threadIdx.x;
  const int wid = tid >> 6, lane = tid & 63;

  if (tid < 128){
    int p = min(p0 + tid, TT*2 - 1);
    s_tok[tid] = row_tok[p];
    s_w[tid]   = row_w[p];
  }
  __syncthreads();

  const char* asrc[4];
#pragma unroll
  for (int i = 0; i < 4; i++){
    int c = wid * 4 + i;
    int r = c * 8 + (lane >> 3);
    int p = min(p0 + r, TT*2 - 1);
    asrc[i] = (const char*)hbuf + (size_t)p * (ID * 2)
            + ((((lane & 7) ^ (lane >> 3)) & 7) << 4);
  }
  const int n0 = (tid & 31) * 4;
  const int k0 = (tid >> 5) * 8;
  const float* bsrc = Wd + (size_t)e * ID * HD + (size_t)k0 * HD + (size_t)nt * 128 + n0;
  int bw[4];
#pragma unroll
  for (int j = 0; j < 4; j++)
    bw[j] = (n0 + j) * 128 + ((((k0 >> 3) ^ (tid & 7) ^ (j << 1)) & 7) << 4);

  const int wm = wid >> 1, wn = wid & 1;
  const int kg = lane >> 4, ln = lane & 15;
  int aoff[2][4], boff[2][4];
#pragma unroll
  for (int ks = 0; ks < 2; ks++){
    int qs = ks * 4 + kg;
#pragma unroll
    for (int f = 0; f < 4; f++){
      int m = wm * 64 + f * 16 + ln;
      aoff[ks][f] = m * 128 + (((qs ^ (ln & 7)) & 7) << 4);
      int n = wn * 64 + f * 16 + ln;
      boff[ks][f] = n * 128 + (((qs ^ swzB(n)) & 7) << 4);
    }
  }

  f4 acc[4][4];
#pragma unroll
  for (int a = 0; a < 4; a++)
#pragma unroll
    for (int b = 0; b < 4; b++) acc[a][b] = f4{0,0,0,0};

#pragma unroll
  for (int i = 0; i < 4; i++) glds16(asrc[i], &sA[0][(wid * 4 + i) * 1024]);
  f4 r0, r1, r2, r3, r4, r5, r6, r7;
  { const f4* p = (const f4*)bsrc;
    r0 = p[0]; r1 = p[HD/4]; r2 = p[HD/2]; r3 = p[3*HD/4];
    r4 = p[HD]; r5 = p[5*HD/4]; r6 = p[3*HD/2]; r7 = p[7*HD/4]; }

  for (int kt = 0; kt < 32; ++kt){
    softbar();
    if (kt + 1 < 32){
      char* dst = &sA[(kt + 1) & 1][0] + (wid * 4) * 1024;
#pragma unroll
      for (int i = 0; i < 4; i++) glds16(asrc[i] + (size_t)(kt + 1) * 128, dst + i * 1024);
    }
#pragma unroll
    for (int j = 0; j < 4; j++){
      *(uint4*)(sB + bw[j]) = uint4{ pk2(r0[j], r1[j]), pk2(r2[j], r3[j]),
                                     pk2(r4[j], r5[j]), pk2(r6[j], r7[j]) };
    }
    softbar();
    if (kt + 1 < 32){
      const f4* p = (const f4*)(bsrc + (size_t)(kt + 1) * 64 * HD);
      r0 = p[0]; r1 = p[HD/4]; r2 = p[HD/2]; r3 = p[3*HD/4];
      r4 = p[HD]; r5 = p[5*HD/4]; r6 = p[3*HD/2]; r7 = p[7*HD/4];
    }
    const char* A = &sA[kt & 1][0];
#pragma unroll
    for (int ks = 0; ks < 2; ks++){
      short8 af[4];
#pragma unroll
      for (int f = 0; f < 4; f++) af[f] = *(const short8*)(A + aoff[ks][f]);
#pragma unroll
      for (int fn = 0; fn < 4; fn++){
        short8 bf = *(const short8*)(sB + boff[ks][fn]);
#pragma unroll
        for (int fm = 0; fm < 4; fm++)
          acc[fm][fn] = __builtin_amdgcn_mfma_f32_16x16x32_bf16(af[fm], bf, acc[fm][fn], 0, 0, 0);
      }
    }
  }
#pragma unroll
  for (int fm = 0; fm < 4; fm++){
#pragma unroll
    for (int r = 0; r < 4; r++){
      int row = wm * 64 + fm * 16 + (lane >> 4) * 4 + r;
      if (row < cntL){
        int tok = s_tok[row];
        float w = s_w[row];
        float* ob = out + (size_t)tok * HD + (size_t)nt * 128 + wn * 64 + ln;
#pragma unroll
        for (int fn = 0; fn < 4; fn++)
          atomicAdd(ob + fn * 16, acc[fm][fn][r] * w);
      }
    }
  }
}

extern "C" void kernel_launch(void* const* d_in, const int* in_sizes, int n_in,
                              void* d_out, int out_size, void* d_ws, size_t ws_size,
                              hipStream_t stream){
  (void)in_sizes; (void)n_in; (void)out_size;
  const float* X  = (const float*)d_in[0];
  const float* RL = (const float*)d_in[1];
  const float* SC = (const float*)d_in[2];
  const float* Wg = (const float*)d_in[3];
  const float* Wu = (const float*)d_in[4];
  const float* Wd = (const float*)d_in[5];
  float* out = (float*)d_out;

  char* ws = (char*)d_ws;
  int*   rid     = (int*)(ws);
  float* rw      = (float*)(ws + 16384);
  int*   row_tok = (int*)(ws + 32768);
  float* row_w   = (float*)(ws + 49152);
  int*   off     = (int*)(ws + 65536);
  __hip_bfloat16* hbuf = (__hip_bfloat16*)(ws + 66560);                      // 16 MiB
  __hip_bfloat16* Xb   = (__hip_bfloat16*)(ws + 66560 + 16777216ull);        // 8 MiB
  __hip_bfloat16* Wb   = (__hip_bfloat16*)(ws + 66560 + 16777216ull + 8388608ull);
  const size_t WME = (size_t)NE * 2048 * 2048;                               // elems per tensor
  const size_t need = 66560ull + 16777216ull + 8388608ull + 3ull * WME * 2ull;

  hipMemsetAsync(d_out, 0, (size_t)TT * HD * sizeof(float), stream);
  k_cvtx <<<2048, 256, 0, stream>>>(X, Xb);
  k_route<<<TT / 256, 256, 0, stream>>>(RL, SC, rid, rw);
  k_lists<<<1, 64, 0, stream>>>(rid, rw, row_tok, row_w, off);

  if (ws_size >= need){
    k_cvtw<<<12288, 256, 0, stream>>>(Wg, Wu, Wd, Wb);
    k_gateup_f<<<1024, 256, 0, stream>>>(Xb, Wb, Wb + WME, row_tok, off, hbuf);
    k_down_f  <<<1024, 256, 0, stream>>>(hbuf, Wb + 2 * WME, row_tok, row_w, off, out);
  } else {
    k_gateup_r3<<<2048, 256, 0, stream>>>(Xb, Wg, Wu, row_tok, off, hbuf);
    k_down_r3  <<<1024, 256, 0, stream>>>(hbuf, Wd, row_tok, row_w, off, out);
  }
}